// Round 12
// baseline (775.902 us; speedup 1.0000x reference)
//
#include <hip/hip_runtime.h>

// ---------------------------------------------------------------------------
// EPROP3_LSTM: e-prop LSTM fwd.  Reformulation:
//   ev_x[b,j,k] = sum_t A_t[b,j] * x_t[b,k],   A_t = d_t * F_t, F_t = prod_{s>t} f_s
//   ev_h[b,j,k] = sum_t A_t[b,j] * h_{t-1}[b,k]
//   ev_b[b,j]   = sum_t A_t[b,j]
// => sequential LSTM recurrence + suffix scan + batched GEMMs (K=T=128).
//
// Round-12 recurrence: 16 WGs x 1024 threads (32 units/WG) -> all-gather
// poll traffic halves to 512KB/step (R10/R11 showed sync cost ~ linear in
// first-round volume).  Recurrence weights pure bf16 (W_hi only; R7 vs R10
// showed output error dominated by ev GEMMs, not recurrence terms).
// Unconditional R10-style polling.  Suffix scan back to the R2-proven
// single-kernel form (fused evb).  K1/K4/K5 MFMA GEMMs unchanged.
// ---------------------------------------------------------------------------

typedef __attribute__((ext_vector_type(8))) short short8;
typedef __attribute__((ext_vector_type(4))) float f32x4;
typedef __attribute__((ext_vector_type(4))) unsigned u32x4;

#define DEV static __device__ __forceinline__

DEV unsigned f2bf(float x) {
  union { float f; unsigned u; } v; v.f = x;
  return (v.u + 0x7fffu + ((v.u >> 16) & 1u)) >> 16;
}
DEV float bf2f(unsigned b) {
  union { float f; unsigned u; } v; v.u = b << 16;
  return v.f;
}
struct HiLo { unsigned hi, lo; };
// pack two floats into (hi-bf16 pair, lo-bf16 pair)
DEV HiLo packpair(float a, float b) {
  unsigned ha = f2bf(a), hb = f2bf(b);
  unsigned la = f2bf(a - bf2f(ha)), lb = f2bf(b - bf2f(hb));
  HiLo r; r.hi = ha | (hb << 16); r.lo = la | (lb << 16);
  return r;
}

#define SENT 0x7F7F7F7Fu

// ---------------------------------------------------------------------------
// Persistent LSTM recurrence.  16 WGs x 1024 threads (16 waves).  WG wg owns
// hidden units [wg*32, wg*32+32) -> 128 gate rows.  Whh slice in registers
// as bf16 (hi) MFMA B-fragments.  Sentinel dataflow sync; hi-only exchange.
// Wave w polls producer w's 2KB slice (2 dwordx4 / lane).
// ---------------------------------------------------------------------------
__global__ __launch_bounds__(1024) void lstm_rec(
    const float* __restrict__ Whh,        // [2048][512]
    const float* __restrict__ XW,         // [128][32][2048]  x@Wih^T + b
    unsigned* __restrict__ Hp,            // [129][16][512] hi slices, SENT-filled
    float* __restrict__ Hf,               // [129][32][512] fp32 (private)
    float* __restrict__ dh,               // [128][32][1536] (private)
    float* __restrict__ fh)               // [128][32][512] (private)
{
  const int wg   = blockIdx.x;            // 0..15
  const int tid  = threadIdx.x;           // 0..1023
  const int lane = tid & 63;
  const int wave = tid >> 6;              // 0..15
  const int tM   = wave & 1;              // batch-tile (0..1)
  const int tN   = wave >> 1;             // row-tile   (0..7)

  __shared__ __align__(16) unsigned Ldh[32 * 256];  // hi bf16 pairs [be][kp]
  __shared__ float gl[32][132];                     // gates tile [b][r]

  const int cc = lane & 15;
  const int kb = lane >> 4;

  // ---- load Whh B-fragments once (bf16 hi) ----
  const int rloc  = tN * 16 + cc;                              // local row 0..127
  const int jglob = (rloc >> 5) * 512 + wg * 32 + (rloc & 31); // global gate row
  short8 whi[16];
#pragma unroll
  for (int s = 0; s < 16; ++s) {
    const float* wp = Whh + (size_t)jglob * 512 + s * 32 + kb * 8;
    f32x4 w0 = *(const f32x4*)wp;
    f32x4 w1 = *(const f32x4*)(wp + 4);
    short8 hi;
#pragma unroll
    for (int j = 0; j < 4; ++j) {
      hi[j]     = (short)f2bf(w0[j]);
      hi[4 + j] = (short)f2bf(w1[j]);
    }
    whi[s] = hi;
  }

  // MFMA A-fragment LDS read base (dword index), XOR-swizzled:
  // chunk c = s*4+kb at row bA lives at dword bA*256 + ((c ^ (bA&7))<<2)
  const int bA = tM * 16 + cc;
  const int mz = bA & 7;
  const unsigned rbase = (unsigned)(bA * 256 + ((kb ^ (mz & 3)) << 2) + ((mz >> 2) << 4));

  // staging write mapping (per lane): row beW, chunks C,C+1 with C=wave*4+half*2
  const int beW  = lane >> 1;
  const int half = lane & 1;
  const int swz  = beW & 7;
  const int C0   = wave * 4 + half * 2;

  const int be = tid >> 5;          // elementwise: batch 0..31
  const int jo = tid & 31;          // elementwise: local hidden unit 0..31
  const int jh = wg * 32 + jo;      // global hidden unit
  float c_reg = 0.f;

  for (int t = 0; t < 128; ++t) {
    // ---- XW prefetch (plain loads; complete under the poll) ----
    const float* xwp = XW + (size_t)t * 65536 + (size_t)be * 2048 + wg * 32 + jo;
    float xwi = xwp[0], xwf = xwp[512], xwg = xwp[1024], xwo = xwp[1536];

    if (t > 0) {
      // ---- poll producer `wave`'s slice until sentinel-free ----
      const unsigned* sp = Hp + ((size_t)t * 16 + wave) * 512 + lane * 8;
      u32x4 h0, h1;
      for (;;) {
#define SLICE_LOAD(dst, addr)                                          \
        asm volatile("global_load_dwordx4 %0, %1, off sc0 sc1"         \
                     : "=&v"(dst) : "v"(addr) : "memory")
        SLICE_LOAD(h0, sp);
        SLICE_LOAD(h1, sp + 4);
#undef SLICE_LOAD
        asm volatile("s_waitcnt vmcnt(0)" ::: "memory");
        // rule #18: fence the register-only sentinel compares BELOW the wait
        __builtin_amdgcn_sched_barrier(0);
        unsigned bad = (unsigned)((h0[0] == SENT) | (h0[1] == SENT) |
                                  (h0[2] == SENT) | (h0[3] == SENT) |
                                  (h1[0] == SENT) | (h1[1] == SENT) |
                                  (h1[2] == SENT) | (h1[3] == SENT));
        if (!__any((int)bad)) break;
        __builtin_amdgcn_s_sleep(1);
      }
      __builtin_amdgcn_sched_barrier(0);

      // ---- scatter to swizzled LDS tile (b128 writes) ----
      const unsigned wb = (unsigned)(beW * 256);
      *(u32x4*)&Ldh[wb + (((C0 + 0) ^ swz) << 2)] = h0;
      *(u32x4*)&Ldh[wb + (((C0 + 1) ^ swz) << 2)] = h1;
    }
    __syncthreads();

    // ---- MFMA: gates_tile = H[t] @ Whh_slice^T (2 independent chains) ----
    f32x4 acc;
    {
      f32x4 a0 = {0.f, 0.f, 0.f, 0.f}, a1 = a0;
      if (t > 0) {
#pragma unroll
        for (int s = 0; s < 16; s += 2) {
          const unsigned i0 = rbase ^ (unsigned)(s << 4);
          const unsigned i1 = rbase ^ (unsigned)((s + 1) << 4);
          short8 ah0 = __builtin_bit_cast(short8, *(const u32x4*)&Ldh[i0]);
          short8 ah1 = __builtin_bit_cast(short8, *(const u32x4*)&Ldh[i1]);
          a0 = __builtin_amdgcn_mfma_f32_16x16x32_bf16(ah0, whi[s],     a0, 0, 0, 0);
          a1 = __builtin_amdgcn_mfma_f32_16x16x32_bf16(ah1, whi[s + 1], a1, 0, 0, 0);
        }
      }
      acc = a0 + a1;
    }
    // D layout: row m = 16*tM + 4*(lane>>4)+r (batch), col n = 16*tN + (lane&15)
#pragma unroll
    for (int r = 0; r < 4; ++r)
      gl[tM * 16 + kb * 4 + r][tN * 16 + cc] = acc[r];
    __syncthreads();

    // ---- elementwise LSTM update: thread = (batch be, unit jo) ----
    {
      float pi = xwi + gl[be][jo];
      float pf = xwf + gl[be][32 + jo];
      float pg = xwg + gl[be][64 + jo];
      float po = xwo + gl[be][96 + jo];
      float ig = 1.f / (1.f + expf(-pi));
      float fg = 1.f / (1.f + expf(-pf));
      float gg = tanhf(pg);
      float og = 1.f / (1.f + expf(-po));
      float di = gg * ig * (1.f - ig);
      float df = c_reg * fg * (1.f - fg);     // uses c_{t-1}
      float dg = ig * (1.f - gg * gg);
      c_reg = fg * c_reg + ig * gg;
      float hn = og * tanhf(c_reg);

      // pack bf16 hi pair with neighbor lane; slice store FIRST (critical)
      unsigned hh = f2bf(hn);
      unsigned hh_nb = (unsigned)__shfl_xor((int)hh, 1);
      if (!(jo & 1)) {
        unsigned stv = hh | (hh_nb << 16);
        size_t sa = ((size_t)(t + 1) * 16 + wg) * 512 + be * 16 + (jo >> 1);
        __hip_atomic_store(&Hp[sa], stv, __ATOMIC_RELAXED, __HIP_MEMORY_SCOPE_AGENT);
      }

      // private stores AFTER the slice store (off the critical path)
      Hf[(size_t)(t + 1) * 16384 + (size_t)be * 512 + jh] = hn;
      size_t db = (size_t)t * 49152 + (size_t)be * 1536 + jh;
      dh[db] = di; dh[db + 512] = df; dh[db + 1024] = dg;
      fh[(size_t)t * 16384 + (size_t)be * 512 + jh] = fg;
    }
  }
}

// ---------------------------------------------------------------------------
// Suffix scan (R2-proven form): A_t = d_t * F_t in place, evb = sum_t A_t.
// One thread per (b, jh); 64 blocks x 256 threads.
// ---------------------------------------------------------------------------
__global__ __launch_bounds__(256) void suffix_A(
    float* __restrict__ dh, const float* __restrict__ fh,
    float* __restrict__ evb)
{
  const int g = blockIdx.x * 256 + threadIdx.x;   // 0..16383
  const int b = g >> 9, jh = g & 511;
  float F = 1.f, s0 = 0.f, s1 = 0.f, s2 = 0.f;
  for (int t = 127; t >= 0; --t) {
    size_t db = (size_t)t * 49152 + (size_t)b * 1536 + jh;
    float a0 = dh[db] * F, a1 = dh[db + 512] * F, a2 = dh[db + 1024] * F;
    dh[db] = a0; dh[db + 512] = a1; dh[db + 1024] = a2;
    s0 += a0; s1 += a1; s2 += a2;
    F *= fh[(size_t)t * 16384 + (size_t)b * 512 + jh];
  }
  size_t eb = (size_t)b * 1536 + jh;
  evb[eb] = s0; evb[eb + 512] = s1; evb[eb + 1024] = s2;
}

// ---------------------------------------------------------------------------
// bf16 hi/lo-split MFMA GEMM (proven in R7).  128x128 tile, BK=32.
// ---------------------------------------------------------------------------
__global__ __launch_bounds__(256, 2) void gemm_bf16s(
    const float* __restrict__ A, const float* __restrict__ B,
    float* __restrict__ C, const float* __restrict__ bias,
    int M, int N, int K,
    long long sAm, long long sAk, long long aBatch,
    long long sBn, long long sBk, long long bBatch,
    long long sCm1, long long sCm2, int M1, long long cBatch)
{
  __shared__ __align__(16) unsigned Ahi[128 * 20], Alo[128 * 20];
  __shared__ __align__(16) unsigned Bhi[128 * 20], Blo[128 * 20];

  const int tid  = threadIdx.x;
  const int lane = tid & 63;
  const int wave = tid >> 6;
  const int wm   = wave >> 1;
  const int wn   = wave & 1;
  const int cc   = lane & 15;
  const int kb   = lane >> 4;
  const long long z = blockIdx.z;
  const float* Ab = A + z * aBatch;
  const float* Bb = B + z * bBatch;
  const int m0 = blockIdx.y * 128, n0 = blockIdx.x * 128;

  f32x4 acc[4][4];
#pragma unroll
  for (int i = 0; i < 4; ++i)
#pragma unroll
    for (int j = 0; j < 4; ++j) acc[i][j] = (f32x4){0.f, 0.f, 0.f, 0.f};

  for (int k0 = 0; k0 < K; k0 += 32) {
    if (sAk == 1) {
      const int r = tid >> 1, half = tid & 1;
      const float* s = Ab + (long long)(m0 + r) * sAm + (k0 + half * 16);
      f32x4 v0 = *(const f32x4*)s;
      f32x4 v1 = *(const f32x4*)(s + 4);
      f32x4 v2 = *(const f32x4*)(s + 8);
      f32x4 v3 = *(const f32x4*)(s + 12);
      u32x4 h0, h1, l0, l1;
      HiLo p;
      p = packpair(v0[0], v0[1]); h0[0] = p.hi; l0[0] = p.lo;
      p = packpair(v0[2], v0[3]); h0[1] = p.hi; l0[1] = p.lo;
      p = packpair(v1[0], v1[1]); h0[2] = p.hi; l0[2] = p.lo;
      p = packpair(v1[2], v1[3]); h0[3] = p.hi; l0[3] = p.lo;
      p = packpair(v2[0], v2[1]); h1[0] = p.hi; l1[0] = p.lo;
      p = packpair(v2[2], v2[3]); h1[1] = p.hi; l1[1] = p.lo;
      p = packpair(v3[0], v3[1]); h1[2] = p.hi; l1[2] = p.lo;
      p = packpair(v3[2], v3[3]); h1[3] = p.hi; l1[3] = p.lo;
      const int o = r * 20 + half * 8;
      *(u32x4*)&Ahi[o] = h0;  *(u32x4*)&Ahi[o + 4] = h1;
      *(u32x4*)&Alo[o] = l0;  *(u32x4*)&Alo[o + 4] = l1;
    } else {
#pragma unroll
      for (int it = 0; it < 2; ++it) {
        const int kp = tid >> 4;
        const int mr = (tid & 15) * 4 + it * 64;
        const float* s0 = Ab + (long long)(k0 + 2 * kp) * sAk + (m0 + mr);
        f32x4 va = *(const f32x4*)s0;
        f32x4 vb = *(const f32x4*)(s0 + sAk);
#pragma unroll
        for (int q = 0; q < 4; ++q) {
          HiLo p = packpair(va[q], vb[q]);
          Ahi[(mr + q) * 20 + kp] = p.hi;
          Alo[(mr + q) * 20 + kp] = p.lo;
        }
      }
    }
    if (sBk == 1) {
      const int r = tid >> 1, half = tid & 1;
      const float* s = Bb + (long long)(n0 + r) * sBn + (k0 + half * 16);
      f32x4 v0 = *(const f32x4*)s;
      f32x4 v1 = *(const f32x4*)(s + 4);
      f32x4 v2 = *(const f32x4*)(s + 8);
      f32x4 v3 = *(const f32x4*)(s + 12);
      u32x4 h0, h1, l0, l1;
      HiLo p;
      p = packpair(v0[0], v0[1]); h0[0] = p.hi; l0[0] = p.lo;
      p = packpair(v0[2], v0[3]); h0[1] = p.hi; l0[1] = p.lo;
      p = packpair(v1[0], v1[1]); h0[2] = p.hi; l0[2] = p.lo;
      p = packpair(v1[2], v1[3]); h0[3] = p.hi; l0[3] = p.lo;
      p = packpair(v2[0], v2[1]); h1[0] = p.hi; l1[0] = p.lo;
      p = packpair(v2[2], v2[3]); h1[1] = p.hi; l1[1] = p.lo;
      p = packpair(v3[0], v3[1]); h1[2] = p.hi; l1[2] = p.lo;
      p = packpair(v3[2], v3[3]); h1[3] = p.hi; l1[3] = p.lo;
      const int o = r * 20 + half * 8;
      *(u32x4*)&Bhi[o] = h0;  *(u32x4*)&Bhi[o + 4] = h1;
      *(u32x4*)&Blo[o] = l0;  *(u32x4*)&Blo[o + 4] = l1;
    } else {
#pragma unroll
      for (int it = 0; it < 2; ++it) {
        const int kp = tid >> 4;
        const int nr = (tid & 15) * 4 + it * 64;
        const float* s0 = Bb + (long long)(k0 + 2 * kp) * sBk + (n0 + nr);
        f32x4 va = *(const f32x4*)s0;
        f32x4 vb = *(const f32x4*)(s0 + sBk);
#pragma unroll
        for (int q = 0; q < 4; ++q) {
          HiLo p = packpair(va[q], vb[q]);
          Bhi[(nr + q) * 20 + kp] = p.hi;
          Blo[(nr + q) * 20 + kp] = p.lo;
        }
      }
    }
    __syncthreads();

    short8 ah[4], al[4], bh[4], bl[4];
#pragma unroll
    for (int mi = 0; mi < 4; ++mi) {
      const int row = wm * 64 + mi * 16 + cc;
      ah[mi] = __builtin_bit_cast(short8, *(const u32x4*)&Ahi[row * 20 + kb * 4]);
      al[mi] = __builtin_bit_cast(short8, *(const u32x4*)&Alo[row * 20 + kb * 4]);
    }
#pragma unroll
    for (int ni = 0; ni < 4; ++ni) {
      const int row = wn * 64 + ni * 16 + cc;
      bh[ni] = __builtin_bit_cast(short8, *(const u32x4*)&Bhi[row * 20 + kb * 4]);
      bl[ni] = __builtin_bit_cast(short8, *(const u32x4*)&Blo[row * 20 + kb * 4]);
    }
#pragma unroll
    for (int mi = 0; mi < 4; ++mi)
#pragma unroll
      for (int ni = 0; ni < 4; ++ni) {
        acc[mi][ni] = __builtin_amdgcn_mfma_f32_16x16x32_bf16(ah[mi], bh[ni], acc[mi][ni], 0, 0, 0);
        acc[mi][ni] = __builtin_amdgcn_mfma_f32_16x16x32_bf16(ah[mi], bl[ni], acc[mi][ni], 0, 0, 0);
        acc[mi][ni] = __builtin_amdgcn_mfma_f32_16x16x32_bf16(al[mi], bh[ni], acc[mi][ni], 0, 0, 0);
      }
    __syncthreads();
  }

#pragma unroll
  for (int ni = 0; ni < 4; ++ni) {
    const int ng = n0 + wn * 64 + ni * 16 + cc;
    const float bv = bias ? bias[ng] : 0.f;
#pragma unroll
    for (int mi = 0; mi < 4; ++mi) {
#pragma unroll
      for (int r = 0; r < 4; ++r) {
        const int mg = m0 + wm * 64 + mi * 16 + kb * 4 + r;
        const long long crow = z * cBatch + (long long)(mg % M1) * sCm1 +
                               (long long)(mg / M1) * sCm2;
        C[crow + ng] = acc[mi][ni][r] + bv;
      }
    }
  }
}

// ---------------------------------------------------------------------------
// Small fp32 GEMM (tiny MLP/readout layers only).
// ---------------------------------------------------------------------------
template <int BM, int BN, int TM, int TN>
__global__ __launch_bounds__(256) void gemm_f32(
    const float* __restrict__ A, const float* __restrict__ B,
    float* __restrict__ C, const float* __restrict__ bias,
    int M, int N, int K,
    long long sAm, long long sAk, long long aBatch,
    long long sBn, long long sBk, long long bBatch,
    long long sCm1, long long sCm2, int M1, long long cBatch,
    int relu)
{
  constexpr int BK = 16;
  __shared__ float As[BK][BM + 4];
  __shared__ float Bs[BK][BN + 4];
  const int tid = threadIdx.x;
  const long long z = blockIdx.z;
  const float* Ab = A + z * aBatch;
  const float* Bb = B + z * bBatch;
  const int m0 = blockIdx.y * BM, n0 = blockIdx.x * BN;
  constexpr int tn_cnt = BN / TN;
  const int tm0 = (tid / tn_cnt) * TM;
  const int tn0 = (tid % tn_cnt) * TN;

  float acc[TM][TN];
#pragma unroll
  for (int i = 0; i < TM; ++i)
#pragma unroll
    for (int j = 0; j < TN; ++j) acc[i][j] = 0.f;

  for (int k0 = 0; k0 < K; k0 += BK) {
    if (sAk == 1) {
      for (int m = tid >> 2; m < BM; m += 64) {
        const int kq = (tid & 3) * 4;
        f32x4 v = {0.f, 0.f, 0.f, 0.f};
        if (m0 + m < M) v = *(const f32x4*)(Ab + (long long)(m0 + m) * sAm + (k0 + kq));
        As[kq + 0][m] = v[0]; As[kq + 1][m] = v[1];
        As[kq + 2][m] = v[2]; As[kq + 3][m] = v[3];
      }
    } else {
      constexpr int mq_cnt = BM / 4;
      for (int kk = tid / mq_cnt; kk < BK; kk += 256 / mq_cnt) {
        const int mq = (tid % mq_cnt) * 4;
        f32x4 v = {0.f, 0.f, 0.f, 0.f};
        if (m0 + mq < M) v = *(const f32x4*)(Ab + (long long)(k0 + kk) * sAk + (m0 + mq));
        *(f32x4*)&As[kk][mq] = v;
      }
    }
    if (sBk == 1) {
      for (int n = tid >> 2; n < BN; n += 64) {
        const int kq = (tid & 3) * 4;
        f32x4 v = {0.f, 0.f, 0.f, 0.f};
        if (n0 + n < N) v = *(const f32x4*)(Bb + (long long)(n0 + n) * sBn + (k0 + kq));
        Bs[kq + 0][n] = v[0]; Bs[kq + 1][n] = v[1];
        Bs[kq + 2][n] = v[2]; Bs[kq + 3][n] = v[3];
      }
    } else {
      constexpr int nq_cnt = BN / 4;
      for (int kk = tid / nq_cnt; kk < BK; kk += 256 / nq_cnt) {
        const int nq = (tid % nq_cnt) * 4;
        f32x4 v = {0.f, 0.f, 0.f, 0.f};
        if (n0 + nq < N) v = *(const f32x4*)(Bb + (long long)(k0 + kk) * sBk + (n0 + nq));
        *(f32x4*)&Bs[kk][nq] = v;
      }
    }
    __syncthreads();

#pragma unroll
    for (int kk = 0; kk < BK; ++kk) {
      float a[TM], bb[TN];
#pragma unroll
      for (int i = 0; i < TM; ++i) a[i] = As[kk][tm0 + i];
#pragma unroll
      for (int j = 0; j < TN; ++j) bb[j] = Bs[kk][tn0 + j];
#pragma unroll
      for (int i = 0; i < TM; ++i)
#pragma unroll
        for (int j = 0; j < TN; ++j) acc[i][j] += a[i] * bb[j];
    }
    __syncthreads();
  }

#pragma unroll
  for (int i = 0; i < TM; ++i) {
    const int mg = m0 + tm0 + i;
    if (mg >= M) continue;
    const long long crow = z * cBatch + (long long)(mg % M1) * sCm1 +
                           (long long)(mg / M1) * sCm2;
#pragma unroll
    for (int j = 0; j < TN; ++j) {
      const int ng = n0 + tn0 + j;
      if (ng >= N) continue;
      float v = acc[i][j];
      if (bias) v += bias[ng];
      if (relu) v = fmaxf(v, 0.f);
      C[crow + ng] = v;
    }
  }
}

// ---------------------------------------------------------------------------
extern "C" void kernel_launch(void* const* d_in, const int* in_sizes, int n_in,
                              void* d_out, int out_size, void* d_ws, size_t ws_size,
                              hipStream_t stream) {
  const float* x   = (const float*)d_in[0];
  const float* Wih = (const float*)d_in[1];
  const float* Whh = (const float*)d_in[2];
  const float* bl  = (const float*)d_in[3];
  const float* Wd  = (const float*)d_in[4];
  const float* bd  = (const float*)d_in[5];
  const float* Ws1 = (const float*)d_in[6];
  const float* bs1 = (const float*)d_in[7];
  const float* Ws2 = (const float*)d_in[8];
  const float* bs2 = (const float*)d_in[9];
  const float* Ws3 = (const float*)d_in[10];
  const float* bs3 = (const float*)d_in[11];
  const float* Ws4 = (const float*)d_in[12];
  const float* bs4 = (const float*)d_in[13];

  float* out = (float*)d_out;
  float* ws  = (float*)d_ws;

  // d_out layout (floats)
  const long long OP = 0, OS = 320, OEX = 16704, OEH = 12599616, OEB = 37765440;

  // scratch inside ev_h output region (dead before final ev_h GEMM writes it)
  float* XW = out + OEH;                              // [128][32][2048]
  float* fh = out + OEH + 8388608;                    // [128][32][512]
  unsigned* Hp = (unsigned*)(out + OEH + 10485760);   // [129][16][512] hi slices

  // ws scratch
  float* dh = ws;                       // [128][32][1536]  d -> A in place
  float* Hf = ws + 6291456;             // [129][32][512] fp32
  float* z1 = ws + 8404992;             // [32][512]
  float* z2 = ws + 8421376;             // [32][256]
  float* z3 = ws + 8429568;             // [32][128]

  // Hp pre-filled with the sentinel byte pattern (0x7F7F7F7F impossible as
  // packed bf16 of h in (-1,1))
  hipMemsetAsync(Hp, 0x7F, 129ull * 16 * 512 * sizeof(unsigned), stream);
  hipMemsetAsync(Hf, 0, 16384 * sizeof(float), stream);    // H[0] = 0

  dim3 blk(256);

  // K1 (MFMA): XW[t][b][j] = x @ Wih^T + b_lstm   (M=4096, N=2048, K=256)
  gemm_bf16s<<<dim3(16, 32, 1), blk, 0, stream>>>(
      x, Wih, XW, bl, 4096, 2048, 256,
      256, 1, 0,            // A: x[m][k], k-contiguous
      256, 1, 0,            // B: Wih[n][k], k-contiguous
      65536, 2048, 128, 0); // C: XW[t=m%128][b=m/128][n]

  // K2: persistent recurrence (16 WGs x 1024 threads, sentinel dataflow)
  lstm_rec<<<dim3(16), dim3(1024), 0, stream>>>(Whh, XW, Hp, Hf, dh, fh);

  // K3: suffix products, A in place, ev_b (single kernel, R2-proven)
  suffix_A<<<dim3(64), blk, 0, stream>>>(dh, fh, out + OEB);

  // MLP + readout on last = Hf[128] (tiny, fp32)
  const float* hlast = Hf + 2097152;
  gemm_f32<32, 32, 2, 2><<<dim3(16, 1, 1), blk, 0, stream>>>(
      hlast, Ws1, z1, bs1, 32, 512, 512, 512, 1, 0, 512, 1, 0, 512, 0, 32, 0, 1);
  gemm_f32<32, 32, 2, 2><<<dim3(8, 1, 1), blk, 0, stream>>>(
      z1, Ws2, z2, bs2, 32, 256, 512, 512, 1, 0, 512, 1, 0, 256, 0, 32, 0, 1);
  gemm_f32<32, 32, 2, 2><<<dim3(4, 1, 1), blk, 0, stream>>>(
      z2, Ws3, z3, bs3, 32, 128, 256, 256, 1, 0, 256, 1, 0, 128, 0, 32, 0, 1);
  gemm_f32<32, 32, 2, 2><<<dim3(16, 1, 1), blk, 0, stream>>>(
      z3, Ws4, out + OS, bs4, 32, 512, 128, 128, 1, 0, 128, 1, 0, 512, 0, 32, 0, 0);
  gemm_f32<32, 32, 2, 2><<<dim3(1, 1, 1), blk, 0, stream>>>(
      hlast, Wd, out + OP, bd, 32, 10, 512, 512, 1, 0, 512, 1, 0, 10, 0, 32, 0, 0);

  // K4 (MFMA): ev_x[b][j][i] = sum_t A[t][b][j] * x[b][t][i]
  gemm_bf16s<<<dim3(2, 12, 32), blk, 0, stream>>>(
      dh, x, out + OEX, nullptr, 1536, 256, 128,
      1, 49152, 1536,       // A: dh[t][b][j], m=j contiguous
      1, 256, 32768,        // B: x[b][t][i], n=i contiguous
      256, 0, 1536, 393216);

  // K5 (MFMA): ev_h[b][j][k] = sum_t A[t][b][j] * h_{t-1}[b][k]
  // (runs last: overwrites XW/fh/Hp scratch living in the ev_h region)
  gemm_bf16s<<<dim3(4, 12, 32), blk, 0, stream>>>(
      dh, Hf, out + OEH, nullptr, 1536, 512, 128,
      1, 49152, 1536,       // A: dh[t][b][j]
      1, 16384, 512,        // B: Hf[t][b][k], n=k contiguous
      512, 0, 1536, 786432);
}

// Round 13
// 677.795 us; speedup vs baseline: 1.1447x; 1.1447x over previous
//
#include <hip/hip_runtime.h>

// ---------------------------------------------------------------------------
// EPROP3_LSTM: e-prop LSTM fwd.  Reformulation:
//   ev_x[b,j,k] = sum_t A_t[b,j] * x_t[b,k],   A_t = d_t * F_t, F_t = prod_{s>t} f_s
//   ev_h[b,j,k] = sum_t A_t[b,j] * h_{t-1}[b,k]
//   ev_b[b,j]   = sum_t A_t[b,j]
// => sequential LSTM recurrence + suffix scan + batched GEMMs (K=T=128).
//
// Round-13 recurrence: 16 WGs x 512 threads (8 waves).  WG owns 32 units
// (128 gate rows); each wave holds TWO weight fragment sets (128 VGPR, the
// R10-proven budget) and issues 2 MFMAs per shared A-fragment read.  Poll
// traffic 512KB/step (R12's target) without R12's VGPR-64 spill cliff.
// Each thread computes 2 adjacent units -> local bf16 pair pack (no shfl),
// float2 private stores.  Sentinel dataflow (R9-proven), hi-only exchange.
// K1/K4/K5 on matrix cores via bf16 hi/lo 3-term split (proven in R7).
// ---------------------------------------------------------------------------

typedef __attribute__((ext_vector_type(8))) short short8;
typedef __attribute__((ext_vector_type(2))) float f32x2;
typedef __attribute__((ext_vector_type(4))) float f32x4;
typedef __attribute__((ext_vector_type(4))) unsigned u32x4;

#define DEV static __device__ __forceinline__

DEV unsigned f2bf(float x) {
  union { float f; unsigned u; } v; v.f = x;
  return (v.u + 0x7fffu + ((v.u >> 16) & 1u)) >> 16;
}
DEV float bf2f(unsigned b) {
  union { float f; unsigned u; } v; v.u = b << 16;
  return v.f;
}
struct HiLo { unsigned hi, lo; };
// pack two floats into (hi-bf16 pair, lo-bf16 pair)
DEV HiLo packpair(float a, float b) {
  unsigned ha = f2bf(a), hb = f2bf(b);
  unsigned la = f2bf(a - bf2f(ha)), lb = f2bf(b - bf2f(hb));
  HiLo r; r.hi = ha | (hb << 16); r.lo = la | (lb << 16);
  return r;
}

#define SENT 0x7F7F7F7Fu

// ---------------------------------------------------------------------------
// Persistent LSTM recurrence.  16 WGs x 512 threads (8 waves).  WG wg owns
// hidden units [wg*32, wg*32+32) -> 128 gate rows.  Whh slice in registers
// as bf16 (hi) MFMA B-fragments, 2 row-tiles per wave.  Sentinel dataflow.
// ---------------------------------------------------------------------------
__global__ __launch_bounds__(512, 2) void lstm_rec(
    const float* __restrict__ Whh,        // [2048][512]
    const float* __restrict__ XW,         // [128][32][2048]  x@Wih^T + b
    unsigned* __restrict__ Hp,            // [129][16][512] hi slices, SENT-filled
    float* __restrict__ Hf,               // [129][32][512] fp32 (private)
    float* __restrict__ dh,               // [128][32][1536] (private)
    float* __restrict__ fh)               // [128][32][512] (private)
{
  const int wg   = blockIdx.x;            // 0..15
  const int tid  = threadIdx.x;           // 0..511
  const int lane = tid & 63;
  const int wave = tid >> 6;              // 0..7
  const int tM   = wave & 1;              // batch-tile (0..1)
  const int tN   = wave >> 1;             // row-tile-pair (0..3)

  __shared__ __align__(16) unsigned Ldh[32 * 256];  // hi bf16 pairs [be][kp]
  __shared__ float gl[32][132];                     // gates tile [b][r]

  const int cc = lane & 15;
  const int kb = lane >> 4;

  // ---- load Whh B-fragments once (bf16 hi), two row-tiles per wave ----
  short8 whiA[16], whiB[16];
#pragma unroll
  for (int q = 0; q < 2; ++q) {
    const int rloc  = (tN * 2 + q) * 16 + cc;                    // 0..127
    const int jglob = (rloc >> 5) * 512 + wg * 32 + (rloc & 31); // gate row
#pragma unroll
    for (int s = 0; s < 16; ++s) {
      const float* wp = Whh + (size_t)jglob * 512 + s * 32 + kb * 8;
      f32x4 w0 = *(const f32x4*)wp;
      f32x4 w1 = *(const f32x4*)(wp + 4);
      short8 hi;
#pragma unroll
      for (int j = 0; j < 4; ++j) {
        hi[j]     = (short)f2bf(w0[j]);
        hi[4 + j] = (short)f2bf(w1[j]);
      }
      if (q == 0) whiA[s] = hi; else whiB[s] = hi;
    }
  }

  // MFMA A-fragment LDS read base (dword index), XOR-swizzled:
  // chunk c = s*4+kb at row bA lives at dword bA*256 + ((c ^ (bA&7))<<2)
  const int bA = tM * 16 + cc;
  const int mz = bA & 7;
  const unsigned rbase = (unsigned)(bA * 256 + ((kb ^ (mz & 3)) << 2) + ((mz >> 2) << 4));

  // staging write mapping (per lane): row beW, producers 2*wave, 2*wave+1
  const int beW  = lane >> 1;
  const int half = lane & 1;
  const int swz  = beW & 7;
  const int Ca   = 4 * (wave * 2)     + half * 2;   // chunks for producer A
  const int Cb   = 4 * (wave * 2 + 1) + half * 2;   // chunks for producer B

  const int be  = tid >> 4;          // elementwise: batch 0..31
  const int jo0 = (tid & 15) * 2;    // elementwise: units jo0, jo0+1
  const int jh0 = wg * 32 + jo0;     // global hidden unit (even)
  float c0 = 0.f, c1 = 0.f;

  for (int t = 0; t < 128; ++t) {
    // ---- XW prefetch (plain loads; complete under the poll) ----
    const float* xwp = XW + (size_t)t * 65536 + (size_t)be * 2048 + wg * 32 + jo0;
    f32x2 xwi = *(const f32x2*)(xwp);
    f32x2 xwf = *(const f32x2*)(xwp + 512);
    f32x2 xwg = *(const f32x2*)(xwp + 1024);
    f32x2 xwo = *(const f32x2*)(xwp + 1536);

    if (t > 0) {
      // ---- poll two producers' slices until sentinel-free ----
      const unsigned* sp0 = Hp + ((size_t)t * 16 + wave * 2) * 512 + lane * 8;
      const unsigned* sp1 = sp0 + 512;
      u32x4 a0, a1, b0, b1;
      for (;;) {
#define SLICE_LOAD(dst, addr)                                          \
        asm volatile("global_load_dwordx4 %0, %1, off sc0 sc1"         \
                     : "=&v"(dst) : "v"(addr) : "memory")
        SLICE_LOAD(a0, sp0);
        SLICE_LOAD(a1, sp0 + 4);
        SLICE_LOAD(b0, sp1);
        SLICE_LOAD(b1, sp1 + 4);
#undef SLICE_LOAD
        asm volatile("s_waitcnt vmcnt(0)" ::: "memory");
        // rule #18: fence the register-only sentinel compares BELOW the wait
        __builtin_amdgcn_sched_barrier(0);
        unsigned bad = (unsigned)((a0[0] == SENT) | (a0[1] == SENT) |
                                  (a0[2] == SENT) | (a0[3] == SENT) |
                                  (a1[0] == SENT) | (a1[1] == SENT) |
                                  (a1[2] == SENT) | (a1[3] == SENT) |
                                  (b0[0] == SENT) | (b0[1] == SENT) |
                                  (b0[2] == SENT) | (b0[3] == SENT) |
                                  (b1[0] == SENT) | (b1[1] == SENT) |
                                  (b1[2] == SENT) | (b1[3] == SENT));
        if (!__any((int)bad)) break;
        __builtin_amdgcn_s_sleep(1);
      }
      __builtin_amdgcn_sched_barrier(0);

      // ---- scatter to swizzled LDS tile (b128 writes) ----
      const unsigned wb = (unsigned)(beW * 256);
      *(u32x4*)&Ldh[wb + (((Ca + 0) ^ swz) << 2)] = a0;
      *(u32x4*)&Ldh[wb + (((Ca + 1) ^ swz) << 2)] = a1;
      *(u32x4*)&Ldh[wb + (((Cb + 0) ^ swz) << 2)] = b0;
      *(u32x4*)&Ldh[wb + (((Cb + 1) ^ swz) << 2)] = b1;
    }
    __syncthreads();

    // ---- MFMA: two row-tiles per wave, shared A-fragment ----
    f32x4 acc0 = {0.f, 0.f, 0.f, 0.f}, acc1 = acc0;
    if (t > 0) {
#pragma unroll
      for (int s = 0; s < 16; ++s) {
        const unsigned idx = rbase ^ (unsigned)(s << 4);
        short8 ah = __builtin_bit_cast(short8, *(const u32x4*)&Ldh[idx]);
        acc0 = __builtin_amdgcn_mfma_f32_16x16x32_bf16(ah, whiA[s], acc0, 0, 0, 0);
        acc1 = __builtin_amdgcn_mfma_f32_16x16x32_bf16(ah, whiB[s], acc1, 0, 0, 0);
      }
    }
    // D layout: row m = 16*tM + 4*(lane>>4)+r (batch), col = tile row + cc
#pragma unroll
    for (int r = 0; r < 4; ++r) {
      gl[tM * 16 + kb * 4 + r][(tN * 2 + 0) * 16 + cc] = acc0[r];
      gl[tM * 16 + kb * 4 + r][(tN * 2 + 1) * 16 + cc] = acc1[r];
    }
    __syncthreads();

    // ---- elementwise LSTM update: thread = (batch be, units jo0, jo0+1) ----
    {
      float pi0 = xwi[0] + gl[be][jo0],       pi1 = xwi[1] + gl[be][jo0 + 1];
      float pf0 = xwf[0] + gl[be][32 + jo0],  pf1 = xwf[1] + gl[be][33 + jo0];
      float pg0 = xwg[0] + gl[be][64 + jo0],  pg1 = xwg[1] + gl[be][65 + jo0];
      float po0 = xwo[0] + gl[be][96 + jo0],  po1 = xwo[1] + gl[be][97 + jo0];
      float ig0 = 1.f / (1.f + expf(-pi0)),   ig1 = 1.f / (1.f + expf(-pi1));
      float fg0 = 1.f / (1.f + expf(-pf0)),   fg1 = 1.f / (1.f + expf(-pf1));
      float gg0 = tanhf(pg0),                 gg1 = tanhf(pg1);
      float og0 = 1.f / (1.f + expf(-po0)),   og1 = 1.f / (1.f + expf(-po1));
      float di0 = gg0 * ig0 * (1.f - ig0),    di1 = gg1 * ig1 * (1.f - ig1);
      float df0 = c0 * fg0 * (1.f - fg0),     df1 = c1 * fg1 * (1.f - fg1);
      float dg0 = ig0 * (1.f - gg0 * gg0),    dg1 = ig1 * (1.f - gg1 * gg1);
      c0 = fg0 * c0 + ig0 * gg0;              c1 = fg1 * c1 + ig1 * gg1;
      float h0 = og0 * tanhf(c0),             h1 = og1 * tanhf(c1);

      // pack bf16 hi pair locally; slice store FIRST (critical path)
      unsigned stv = f2bf(h0) | (f2bf(h1) << 16);
      size_t sa = ((size_t)(t + 1) * 16 + wg) * 512 + be * 16 + (jo0 >> 1);
      __hip_atomic_store(&Hp[sa], stv, __ATOMIC_RELAXED, __HIP_MEMORY_SCOPE_AGENT);

      // private stores AFTER the slice store (off the critical path)
      size_t ho = (size_t)(t + 1) * 16384 + (size_t)be * 512 + jh0;
      *(f32x2*)&Hf[ho] = (f32x2){h0, h1};
      size_t db = (size_t)t * 49152 + (size_t)be * 1536 + jh0;
      *(f32x2*)&dh[db]        = (f32x2){di0, di1};
      *(f32x2*)&dh[db + 512]  = (f32x2){df0, df1};
      *(f32x2*)&dh[db + 1024] = (f32x2){dg0, dg1};
      *(f32x2*)&fh[(size_t)t * 16384 + (size_t)be * 512 + jh0] = (f32x2){fg0, fg1};
    }
  }
}

// ---------------------------------------------------------------------------
// Suffix scan: A_t = d_t * F_t in place, evb = sum_t A_t.
// ---------------------------------------------------------------------------
__global__ __launch_bounds__(256) void suffix_A(
    float* __restrict__ dh, const float* __restrict__ fh,
    float* __restrict__ evb)
{
  const int g = blockIdx.x * 256 + threadIdx.x;   // 0..16383
  const int b = g >> 9, jh = g & 511;
  float F = 1.f, s0 = 0.f, s1 = 0.f, s2 = 0.f;
  for (int t = 127; t >= 0; --t) {
    size_t db = (size_t)t * 49152 + (size_t)b * 1536 + jh;
    float a0 = dh[db] * F, a1 = dh[db + 512] * F, a2 = dh[db + 1024] * F;
    dh[db] = a0; dh[db + 512] = a1; dh[db + 1024] = a2;
    s0 += a0; s1 += a1; s2 += a2;
    F *= fh[(size_t)t * 16384 + (size_t)b * 512 + jh];
  }
  size_t eb = (size_t)b * 1536 + jh;
  evb[eb] = s0; evb[eb + 512] = s1; evb[eb + 1024] = s2;
}

// ---------------------------------------------------------------------------
// bf16 hi/lo-split MFMA GEMM (proven in R7).  128x128 tile, BK=32.
// ---------------------------------------------------------------------------
__global__ __launch_bounds__(256, 2) void gemm_bf16s(
    const float* __restrict__ A, const float* __restrict__ B,
    float* __restrict__ C, const float* __restrict__ bias,
    int M, int N, int K,
    long long sAm, long long sAk, long long aBatch,
    long long sBn, long long sBk, long long bBatch,
    long long sCm1, long long sCm2, int M1, long long cBatch)
{
  __shared__ __align__(16) unsigned Ahi[128 * 20], Alo[128 * 20];
  __shared__ __align__(16) unsigned Bhi[128 * 20], Blo[128 * 20];

  const int tid  = threadIdx.x;
  const int lane = tid & 63;
  const int wave = tid >> 6;
  const int wm   = wave >> 1;
  const int wn   = wave & 1;
  const int cc   = lane & 15;
  const int kb   = lane >> 4;
  const long long z = blockIdx.z;
  const float* Ab = A + z * aBatch;
  const float* Bb = B + z * bBatch;
  const int m0 = blockIdx.y * 128, n0 = blockIdx.x * 128;

  f32x4 acc[4][4];
#pragma unroll
  for (int i = 0; i < 4; ++i)
#pragma unroll
    for (int j = 0; j < 4; ++j) acc[i][j] = (f32x4){0.f, 0.f, 0.f, 0.f};

  for (int k0 = 0; k0 < K; k0 += 32) {
    if (sAk == 1) {
      const int r = tid >> 1, half = tid & 1;
      const float* s = Ab + (long long)(m0 + r) * sAm + (k0 + half * 16);
      f32x4 v0 = *(const f32x4*)s;
      f32x4 v1 = *(const f32x4*)(s + 4);
      f32x4 v2 = *(const f32x4*)(s + 8);
      f32x4 v3 = *(const f32x4*)(s + 12);
      u32x4 h0, h1, l0, l1;
      HiLo p;
      p = packpair(v0[0], v0[1]); h0[0] = p.hi; l0[0] = p.lo;
      p = packpair(v0[2], v0[3]); h0[1] = p.hi; l0[1] = p.lo;
      p = packpair(v1[0], v1[1]); h0[2] = p.hi; l0[2] = p.lo;
      p = packpair(v1[2], v1[3]); h0[3] = p.hi; l0[3] = p.lo;
      p = packpair(v2[0], v2[1]); h1[0] = p.hi; l1[0] = p.lo;
      p = packpair(v2[2], v2[3]); h1[1] = p.hi; l1[1] = p.lo;
      p = packpair(v3[0], v3[1]); h1[2] = p.hi; l1[2] = p.lo;
      p = packpair(v3[2], v3[3]); h1[3] = p.hi; l1[3] = p.lo;
      const int o = r * 20 + half * 8;
      *(u32x4*)&Ahi[o] = h0;  *(u32x4*)&Ahi[o + 4] = h1;
      *(u32x4*)&Alo[o] = l0;  *(u32x4*)&Alo[o + 4] = l1;
    } else {
#pragma unroll
      for (int it = 0; it < 2; ++it) {
        const int kp = tid >> 4;
        const int mr = (tid & 15) * 4 + it * 64;
        const float* s0 = Ab + (long long)(k0 + 2 * kp) * sAk + (m0 + mr);
        f32x4 va = *(const f32x4*)s0;
        f32x4 vb = *(const f32x4*)(s0 + sAk);
#pragma unroll
        for (int q = 0; q < 4; ++q) {
          HiLo p = packpair(va[q], vb[q]);
          Ahi[(mr + q) * 20 + kp] = p.hi;
          Alo[(mr + q) * 20 + kp] = p.lo;
        }
      }
    }
    if (sBk == 1) {
      const int r = tid >> 1, half = tid & 1;
      const float* s = Bb + (long long)(n0 + r) * sBn + (k0 + half * 16);
      f32x4 v0 = *(const f32x4*)s;
      f32x4 v1 = *(const f32x4*)(s + 4);
      f32x4 v2 = *(const f32x4*)(s + 8);
      f32x4 v3 = *(const f32x4*)(s + 12);
      u32x4 h0, h1, l0, l1;
      HiLo p;
      p = packpair(v0[0], v0[1]); h0[0] = p.hi; l0[0] = p.lo;
      p = packpair(v0[2], v0[3]); h0[1] = p.hi; l0[1] = p.lo;
      p = packpair(v1[0], v1[1]); h0[2] = p.hi; l0[2] = p.lo;
      p = packpair(v1[2], v1[3]); h0[3] = p.hi; l0[3] = p.lo;
      p = packpair(v2[0], v2[1]); h1[0] = p.hi; l1[0] = p.lo;
      p = packpair(v2[2], v2[3]); h1[1] = p.hi; l1[1] = p.lo;
      p = packpair(v3[0], v3[1]); h1[2] = p.hi; l1[2] = p.lo;
      p = packpair(v3[2], v3[3]); h1[3] = p.hi; l1[3] = p.lo;
      const int o = r * 20 + half * 8;
      *(u32x4*)&Bhi[o] = h0;  *(u32x4*)&Bhi[o + 4] = h1;
      *(u32x4*)&Blo[o] = l0;  *(u32x4*)&Blo[o + 4] = l1;
    } else {
#pragma unroll
      for (int it = 0; it < 2; ++it) {
        const int kp = tid >> 4;
        const int nr = (tid & 15) * 4 + it * 64;
        const float* s0 = Bb + (long long)(k0 + 2 * kp) * sBk + (n0 + nr);
        f32x4 va = *(const f32x4*)s0;
        f32x4 vb = *(const f32x4*)(s0 + sBk);
#pragma unroll
        for (int q = 0; q < 4; ++q) {
          HiLo p = packpair(va[q], vb[q]);
          Bhi[(nr + q) * 20 + kp] = p.hi;
          Blo[(nr + q) * 20 + kp] = p.lo;
        }
      }
    }
    __syncthreads();

    short8 ah[4], al[4], bh[4], bl[4];
#pragma unroll
    for (int mi = 0; mi < 4; ++mi) {
      const int row = wm * 64 + mi * 16 + cc;
      ah[mi] = __builtin_bit_cast(short8, *(const u32x4*)&Ahi[row * 20 + kb * 4]);
      al[mi] = __builtin_bit_cast(short8, *(const u32x4*)&Alo[row * 20 + kb * 4]);
    }
#pragma unroll
    for (int ni = 0; ni < 4; ++ni) {
      const int row = wn * 64 + ni * 16 + cc;
      bh[ni] = __builtin_bit_cast(short8, *(const u32x4*)&Bhi[row * 20 + kb * 4]);
      bl[ni] = __builtin_bit_cast(short8, *(const u32x4*)&Blo[row * 20 + kb * 4]);
    }
#pragma unroll
    for (int mi = 0; mi < 4; ++mi)
#pragma unroll
      for (int ni = 0; ni < 4; ++ni) {
        acc[mi][ni] = __builtin_amdgcn_mfma_f32_16x16x32_bf16(ah[mi], bh[ni], acc[mi][ni], 0, 0, 0);
        acc[mi][ni] = __builtin_amdgcn_mfma_f32_16x16x32_bf16(ah[mi], bl[ni], acc[mi][ni], 0, 0, 0);
        acc[mi][ni] = __builtin_amdgcn_mfma_f32_16x16x32_bf16(al[mi], bh[ni], acc[mi][ni], 0, 0, 0);
      }
    __syncthreads();
  }

#pragma unroll
  for (int ni = 0; ni < 4; ++ni) {
    const int ng = n0 + wn * 64 + ni * 16 + cc;
    const float bv = bias ? bias[ng] : 0.f;
#pragma unroll
    for (int mi = 0; mi < 4; ++mi) {
#pragma unroll
      for (int r = 0; r < 4; ++r) {
        const int mg = m0 + wm * 64 + mi * 16 + kb * 4 + r;
        const long long crow = z * cBatch + (long long)(mg % M1) * sCm1 +
                               (long long)(mg / M1) * sCm2;
        C[crow + ng] = acc[mi][ni][r] + bv;
      }
    }
  }
}

// ---------------------------------------------------------------------------
// Small fp32 GEMM (tiny MLP/readout layers only).
// ---------------------------------------------------------------------------
template <int BM, int BN, int TM, int TN>
__global__ __launch_bounds__(256) void gemm_f32(
    const float* __restrict__ A, const float* __restrict__ B,
    float* __restrict__ C, const float* __restrict__ bias,
    int M, int N, int K,
    long long sAm, long long sAk, long long aBatch,
    long long sBn, long long sBk, long long bBatch,
    long long sCm1, long long sCm2, int M1, long long cBatch,
    int relu)
{
  constexpr int BK = 16;
  __shared__ float As[BK][BM + 4];
  __shared__ float Bs[BK][BN + 4];
  const int tid = threadIdx.x;
  const long long z = blockIdx.z;
  const float* Ab = A + z * aBatch;
  const float* Bb = B + z * bBatch;
  const int m0 = blockIdx.y * BM, n0 = blockIdx.x * BN;
  constexpr int tn_cnt = BN / TN;
  const int tm0 = (tid / tn_cnt) * TM;
  const int tn0 = (tid % tn_cnt) * TN;

  float acc[TM][TN];
#pragma unroll
  for (int i = 0; i < TM; ++i)
#pragma unroll
    for (int j = 0; j < TN; ++j) acc[i][j] = 0.f;

  for (int k0 = 0; k0 < K; k0 += BK) {
    if (sAk == 1) {
      for (int m = tid >> 2; m < BM; m += 64) {
        const int kq = (tid & 3) * 4;
        f32x4 v = {0.f, 0.f, 0.f, 0.f};
        if (m0 + m < M) v = *(const f32x4*)(Ab + (long long)(m0 + m) * sAm + (k0 + kq));
        As[kq + 0][m] = v[0]; As[kq + 1][m] = v[1];
        As[kq + 2][m] = v[2]; As[kq + 3][m] = v[3];
      }
    } else {
      constexpr int mq_cnt = BM / 4;
      for (int kk = tid / mq_cnt; kk < BK; kk += 256 / mq_cnt) {
        const int mq = (tid % mq_cnt) * 4;
        f32x4 v = {0.f, 0.f, 0.f, 0.f};
        if (m0 + mq < M) v = *(const f32x4*)(Ab + (long long)(k0 + kk) * sAk + (m0 + mq));
        *(f32x4*)&As[kk][mq] = v;
      }
    }
    if (sBk == 1) {
      for (int n = tid >> 2; n < BN; n += 64) {
        const int kq = (tid & 3) * 4;
        f32x4 v = {0.f, 0.f, 0.f, 0.f};
        if (n0 + n < N) v = *(const f32x4*)(Bb + (long long)(n0 + n) * sBn + (k0 + kq));
        Bs[kq + 0][n] = v[0]; Bs[kq + 1][n] = v[1];
        Bs[kq + 2][n] = v[2]; Bs[kq + 3][n] = v[3];
      }
    } else {
      constexpr int nq_cnt = BN / 4;
      for (int kk = tid / nq_cnt; kk < BK; kk += 256 / nq_cnt) {
        const int nq = (tid % nq_cnt) * 4;
        f32x4 v = {0.f, 0.f, 0.f, 0.f};
        if (n0 + nq < N) v = *(const f32x4*)(Bb + (long long)(k0 + kk) * sBk + (n0 + nq));
        *(f32x4*)&Bs[kk][nq] = v;
      }
    }
    __syncthreads();

#pragma unroll
    for (int kk = 0; kk < BK; ++kk) {
      float a[TM], bb[TN];
#pragma unroll
      for (int i = 0; i < TM; ++i) a[i] = As[kk][tm0 + i];
#pragma unroll
      for (int j = 0; j < TN; ++j) bb[j] = Bs[kk][tn0 + j];
#pragma unroll
      for (int i = 0; i < TM; ++i)
#pragma unroll
        for (int j = 0; j < TN; ++j) acc[i][j] += a[i] * bb[j];
    }
    __syncthreads();
  }

#pragma unroll
  for (int i = 0; i < TM; ++i) {
    const int mg = m0 + tm0 + i;
    if (mg >= M) continue;
    const long long crow = z * cBatch + (long long)(mg % M1) * sCm1 +
                           (long long)(mg / M1) * sCm2;
#pragma unroll
    for (int j = 0; j < TN; ++j) {
      const int ng = n0 + tn0 + j;
      if (ng >= N) continue;
      float v = acc[i][j];
      if (bias) v += bias[ng];
      if (relu) v = fmaxf(v, 0.f);
      C[crow + ng] = v;
    }
  }
}

// ---------------------------------------------------------------------------
extern "C" void kernel_launch(void* const* d_in, const int* in_sizes, int n_in,
                              void* d_out, int out_size, void* d_ws, size_t ws_size,
                              hipStream_t stream) {
  const float* x   = (const float*)d_in[0];
  const float* Wih = (const float*)d_in[1];
  const float* Whh = (const float*)d_in[2];
  const float* bl  = (const float*)d_in[3];
  const float* Wd  = (const float*)d_in[4];
  const float* bd  = (const float*)d_in[5];
  const float* Ws1 = (const float*)d_in[6];
  const float* bs1 = (const float*)d_in[7];
  const float* Ws2 = (const float*)d_in[8];
  const float* bs2 = (const float*)d_in[9];
  const float* Ws3 = (const float*)d_in[10];
  const float* bs3 = (const float*)d_in[11];
  const float* Ws4 = (const float*)d_in[12];
  const float* bs4 = (const float*)d_in[13];

  float* out = (float*)d_out;
  float* ws  = (float*)d_ws;

  // d_out layout (floats)
  const long long OP = 0, OS = 320, OEX = 16704, OEH = 12599616, OEB = 37765440;

  // scratch inside ev_h output region (dead before final ev_h GEMM writes it)
  float* XW = out + OEH;                              // [128][32][2048]
  float* fh = out + OEH + 8388608;                    // [128][32][512]
  unsigned* Hp = (unsigned*)(out + OEH + 10485760);   // [129][16][512] hi slices

  // ws scratch
  float* dh = ws;                       // [128][32][1536]  d -> A in place
  float* Hf = ws + 6291456;             // [129][32][512] fp32
  float* z1 = ws + 8404992;             // [32][512]
  float* z2 = ws + 8421376;             // [32][256]
  float* z3 = ws + 8429568;             // [32][128]

  // Hp pre-filled with the sentinel byte pattern (0x7F7F7F7F impossible as
  // packed bf16 of h in (-1,1))
  hipMemsetAsync(Hp, 0x7F, 129ull * 16 * 512 * sizeof(unsigned), stream);
  hipMemsetAsync(Hf, 0, 16384 * sizeof(float), stream);    // H[0] = 0

  dim3 blk(256);

  // K1 (MFMA): XW[t][b][j] = x @ Wih^T + b_lstm   (M=4096, N=2048, K=256)
  gemm_bf16s<<<dim3(16, 32, 1), blk, 0, stream>>>(
      x, Wih, XW, bl, 4096, 2048, 256,
      256, 1, 0,            // A: x[m][k], k-contiguous
      256, 1, 0,            // B: Wih[n][k], k-contiguous
      65536, 2048, 128, 0); // C: XW[t=m%128][b=m/128][n]

  // K2: persistent recurrence (16 WGs x 512 threads, sentinel dataflow)
  lstm_rec<<<dim3(16), dim3(512), 0, stream>>>(Whh, XW, Hp, Hf, dh, fh);

  // K3: suffix products, A in place, ev_b
  suffix_A<<<dim3(64), blk, 0, stream>>>(dh, fh, out + OEB);

  // MLP + readout on last = Hf[128] (tiny, fp32)
  const float* hlast = Hf + 2097152;
  gemm_f32<32, 32, 2, 2><<<dim3(16, 1, 1), blk, 0, stream>>>(
      hlast, Ws1, z1, bs1, 32, 512, 512, 512, 1, 0, 512, 1, 0, 512, 0, 32, 0, 1);
  gemm_f32<32, 32, 2, 2><<<dim3(8, 1, 1), blk, 0, stream>>>(
      z1, Ws2, z2, bs2, 32, 256, 512, 512, 1, 0, 512, 1, 0, 256, 0, 32, 0, 1);
  gemm_f32<32, 32, 2, 2><<<dim3(4, 1, 1), blk, 0, stream>>>(
      z2, Ws3, z3, bs3, 32, 128, 256, 256, 1, 0, 256, 1, 0, 128, 0, 32, 0, 1);
  gemm_f32<32, 32, 2, 2><<<dim3(16, 1, 1), blk, 0, stream>>>(
      z3, Ws4, out + OS, bs4, 32, 512, 128, 128, 1, 0, 128, 1, 0, 512, 0, 32, 0, 0);
  gemm_f32<32, 32, 2, 2><<<dim3(1, 1, 1), blk, 0, stream>>>(
      hlast, Wd, out + OP, bd, 32, 10, 512, 512, 1, 0, 512, 1, 0, 10, 0, 32, 0, 0);

  // K4 (MFMA): ev_x[b][j][i] = sum_t A[t][b][j] * x[b][t][i]
  gemm_bf16s<<<dim3(2, 12, 32), blk, 0, stream>>>(
      dh, x, out + OEX, nullptr, 1536, 256, 128,
      1, 49152, 1536,       // A: dh[t][b][j], m=j contiguous
      1, 256, 32768,        // B: x[b][t][i], n=i contiguous
      256, 0, 1536, 393216);

  // K5 (MFMA): ev_h[b][j][k] = sum_t A[t][b][j] * h_{t-1}[b][k]
  // (runs last: overwrites XW/fh/Hp scratch living in the ev_h region)
  gemm_bf16s<<<dim3(4, 12, 32), blk, 0, stream>>>(
      dh, Hf, out + OEH, nullptr, 1536, 512, 128,
      1, 49152, 1536,       // A: dh[t][b][j]
      1, 16384, 512,        // B: Hf[t][b][k], n=k contiguous
      512, 0, 1536, 786432);
}

// Round 14
// 635.156 us; speedup vs baseline: 1.2216x; 1.0671x over previous
//
#include <hip/hip_runtime.h>

// ---------------------------------------------------------------------------
// EPROP3_LSTM: e-prop LSTM fwd.  Reformulation:
//   ev_x[b,j,k] = sum_t A_t[b,j] * x_t[b,k],   A_t = d_t * F_t, F_t = prod_{s>t} f_s
//   ev_h[b,j,k] = sum_t A_t[b,j] * h_{t-1}[b,k]
//   ev_b[b,j]   = sum_t A_t[b,j]
// => sequential LSTM recurrence + suffix scan + batched GEMMs (K=T=128).
//
// Round-14: recurrence reverted to the EXACT R10 kernel (best measured:
// 400us; R11/R12/R13 variants all slower -> converged at the fixed per-step
// latency quantum).  Suffix scan re-parallelized: 8-chunk 3-kernel form
// (serial depth 128 -> 16, 512 blocks).  K1/K4/K5 MFMA GEMMs unchanged.
// ---------------------------------------------------------------------------

typedef __attribute__((ext_vector_type(8))) short short8;
typedef __attribute__((ext_vector_type(4))) float f32x4;
typedef __attribute__((ext_vector_type(4))) unsigned u32x4;

#define DEV static __device__ __forceinline__

DEV unsigned f2bf(float x) {
  union { float f; unsigned u; } v; v.f = x;
  return (v.u + 0x7fffu + ((v.u >> 16) & 1u)) >> 16;
}
DEV float bf2f(unsigned b) {
  union { float f; unsigned u; } v; v.u = b << 16;
  return v.f;
}
struct HiLo { unsigned hi, lo; };
// pack two floats into (hi-bf16 pair, lo-bf16 pair)
DEV HiLo packpair(float a, float b) {
  unsigned ha = f2bf(a), hb = f2bf(b);
  unsigned la = f2bf(a - bf2f(ha)), lb = f2bf(b - bf2f(hb));
  HiLo r; r.hi = ha | (hb << 16); r.lo = la | (lb << 16);
  return r;
}

#define SENT 0x7F7F7F7Fu

// ---------------------------------------------------------------------------
// Persistent LSTM recurrence (EXACT R10 kernel, best measured).
// 32 WGs x 512 threads.  WG wg owns units [wg*16, wg*16+16) -> 64 gate rows.
// Whh slice in registers as bf16 hi/lo MFMA B-fragments; hi-only h exchange;
// sentinel dataflow sync.
// ---------------------------------------------------------------------------
__global__ __launch_bounds__(512, 1) void lstm_rec(
    const float* __restrict__ Whh,        // [2048][512]
    const float* __restrict__ XW,         // [128][32][2048]  x@Wih^T + b
    unsigned* __restrict__ Hp,            // [129][32][256] hi slices, SENT-filled
    float* __restrict__ Hf,               // [129][32][512] fp32 (private)
    float* __restrict__ dh,               // [128][32][1536] (private)
    float* __restrict__ fh)               // [128][32][512] (private)
{
  const int wg   = blockIdx.x;            // 0..31
  const int tid  = threadIdx.x;           // 0..511
  const int lane = tid & 63;
  const int wave = tid >> 6;              // 0..7
  const int tM   = wave & 1;              // batch-tile (0..1)
  const int tN   = wave >> 1;             // row-tile   (0..3)

  __shared__ __align__(16) unsigned Ldh[32 * 256];  // hi bf16 pairs [be][kp]
  __shared__ float gl[32][68];                      // gates tile [b][r]

  const int cc = lane & 15;
  const int kb = lane >> 4;

  // ---- load Whh B-fragments once (hi/lo bf16 split) ----
  const int rloc  = tN * 16 + cc;                              // local row 0..63
  const int jglob = (rloc >> 4) * 512 + wg * 16 + (rloc & 15); // global gate row
  short8 whi[16], wlo[16];
#pragma unroll
  for (int s = 0; s < 16; ++s) {
    const float* wp = Whh + (size_t)jglob * 512 + s * 32 + kb * 8;
    f32x4 w0 = *(const f32x4*)wp;
    f32x4 w1 = *(const f32x4*)(wp + 4);
    short8 hi, lo;
#pragma unroll
    for (int j = 0; j < 4; ++j) {
      unsigned h0 = f2bf(w0[j]);
      hi[j] = (short)h0;  lo[j] = (short)f2bf(w0[j] - bf2f(h0));
      unsigned h1 = f2bf(w1[j]);
      hi[4 + j] = (short)h1;  lo[4 + j] = (short)f2bf(w1[j] - bf2f(h1));
    }
    whi[s] = hi; wlo[s] = lo;
  }

  // MFMA A-fragment LDS read base (dword index), XOR-swizzled
  const int bA = tM * 16 + cc;
  const int mz = bA & 7;
  const unsigned rbase = (unsigned)(bA * 256 + ((kb ^ (mz & 3)) << 2) + ((mz >> 2) << 4));

  // staging write mapping (per lane): row beW, chunk c ^ (beW&7)
  const int beW = lane >> 1;
  const int swz = beW & 7;

  const int be = tid >> 4;          // elementwise: batch 0..31
  const int jo = tid & 15;          // elementwise: local hidden unit 0..15
  const int jh = wg * 16 + jo;      // global hidden unit
  float c_reg = 0.f;

  for (int t = 0; t < 128; ++t) {
    // ---- XW prefetch (plain loads; complete under the poll) ----
    const float* xwp = XW + (size_t)t * 65536 + (size_t)be * 2048 + wg * 16 + jo;
    float xwi = xwp[0], xwf = xwp[512], xwg = xwp[1024], xwo = xwp[1536];

    if (t > 0) {
      // ---- poll the DATA of this wave's 4 producers until sentinel-free ----
      const unsigned* sp = Hp + ((size_t)t * 32 + wave * 4) * 256 + lane * 4;
      u32x4 h0, h1, h2, h3;
      for (;;) {
#define SLICE_LOAD(dst, addr)                                          \
        asm volatile("global_load_dwordx4 %0, %1, off sc0 sc1"         \
                     : "=&v"(dst) : "v"(addr) : "memory")
        SLICE_LOAD(h0, sp);
        SLICE_LOAD(h1, sp + 256);
        SLICE_LOAD(h2, sp + 512);
        SLICE_LOAD(h3, sp + 768);
#undef SLICE_LOAD
        asm volatile("s_waitcnt vmcnt(0)" ::: "memory");
        // rule #18: fence the register-only sentinel compares BELOW the wait
        __builtin_amdgcn_sched_barrier(0);
        unsigned bad = (unsigned)((h0[0] == SENT) | (h0[1] == SENT) |
                                  (h0[2] == SENT) | (h0[3] == SENT) |
                                  (h1[0] == SENT) | (h1[1] == SENT) |
                                  (h1[2] == SENT) | (h1[3] == SENT) |
                                  (h2[0] == SENT) | (h2[1] == SENT) |
                                  (h2[2] == SENT) | (h2[3] == SENT) |
                                  (h3[0] == SENT) | (h3[1] == SENT) |
                                  (h3[2] == SENT) | (h3[3] == SENT));
        if (!__any((int)bad)) break;
        __builtin_amdgcn_s_sleep(1);
      }
      __builtin_amdgcn_sched_barrier(0);

      // ---- scatter to swizzled LDS tile (b128 writes) ----
      const int c0 = wave * 8 + (lane & 1);   // producer (wave*4+i) -> chunk c0+2i
      const unsigned wb = (unsigned)(beW * 256);
      *(u32x4*)&Ldh[wb + (((c0 + 0) ^ swz) << 2)] = h0;
      *(u32x4*)&Ldh[wb + (((c0 + 2) ^ swz) << 2)] = h1;
      *(u32x4*)&Ldh[wb + (((c0 + 4) ^ swz) << 2)] = h2;
      *(u32x4*)&Ldh[wb + (((c0 + 6) ^ swz) << 2)] = h3;
    }
    __syncthreads();

    // ---- MFMA: gates_tile = H[t] @ Whh_slice^T (2 independent chains) ----
    f32x4 acc;
    {
      f32x4 a0 = {0.f, 0.f, 0.f, 0.f}, a1 = a0;
      if (t > 0) {
#pragma unroll
        for (int s = 0; s < 16; ++s) {
          const unsigned idx = rbase ^ (unsigned)(s << 4);
          short8 ah = __builtin_bit_cast(short8, *(const u32x4*)&Ldh[idx]);
          a0 = __builtin_amdgcn_mfma_f32_16x16x32_bf16(ah, whi[s], a0, 0, 0, 0);
          a1 = __builtin_amdgcn_mfma_f32_16x16x32_bf16(ah, wlo[s], a1, 0, 0, 0);
        }
      }
      acc = a0 + a1;
    }
    // D layout: row m = 16*tM + 4*(lane>>4)+r (batch), col n = 16*tN + (lane&15)
#pragma unroll
    for (int r = 0; r < 4; ++r)
      gl[tM * 16 + kb * 4 + r][tN * 16 + cc] = acc[r];
    __syncthreads();

    // ---- elementwise LSTM update: thread = (batch be, unit jo) ----
    {
      float pi = xwi + gl[be][jo];
      float pf = xwf + gl[be][16 + jo];
      float pg = xwg + gl[be][32 + jo];
      float po = xwo + gl[be][48 + jo];
      float ig = 1.f / (1.f + expf(-pi));
      float fg = 1.f / (1.f + expf(-pf));
      float gg = tanhf(pg);
      float og = 1.f / (1.f + expf(-po));
      float di = gg * ig * (1.f - ig);
      float df = c_reg * fg * (1.f - fg);     // uses c_{t-1}
      float dg = ig * (1.f - gg * gg);
      c_reg = fg * c_reg + ig * gg;
      float hn = og * tanhf(c_reg);

      // pack bf16 hi pair with neighbor lane; slice store FIRST (critical)
      unsigned hh = f2bf(hn);
      unsigned hh_nb = (unsigned)__shfl_xor((int)hh, 1);
      if (!(tid & 1)) {
        unsigned stv = hh | (hh_nb << 16);
        size_t sa = ((size_t)(t + 1) * 32 + wg) * 256 + (tid >> 1);
        __hip_atomic_store(&Hp[sa], stv, __ATOMIC_RELAXED, __HIP_MEMORY_SCOPE_AGENT);
      }

      // private stores AFTER the slice store (off the critical path)
      Hf[(size_t)(t + 1) * 16384 + (size_t)be * 512 + jh] = hn;
      size_t db = (size_t)t * 49152 + (size_t)be * 1536 + jh;
      dh[db] = di; dh[db + 512] = df; dh[db + 1024] = dg;
      fh[(size_t)t * 16384 + (size_t)be * 512 + jh] = fg;
    }
  }
}

// ---------------------------------------------------------------------------
// Suffix scan, 8-way chunked over t (chunk = 16 steps).
// pre:  Cp[k][b][jh] = prod_{t in chunk k} f_t          (512 blocks)
// main: F = prod_{k'>k} Cp[k'], scan 16 steps, A in place, partials -> Sp
// red:  evb = sum_k Sp[k]                               (192 blocks)
// ---------------------------------------------------------------------------
__global__ __launch_bounds__(256) void suffix_pre(
    const float* __restrict__ fh, float* __restrict__ Cp)
{
  const int g = blockIdx.x * 256 + threadIdx.x;   // 0..131071 = (k,b,jh)
  const int k = g >> 14, bjh = g & 16383;
  const int b = bjh >> 9, jh = bjh & 511;
  float P = 1.f;
  for (int t = k * 16; t < k * 16 + 16; ++t)
    P *= fh[(size_t)t * 16384 + (size_t)b * 512 + jh];
  Cp[g] = P;
}

__global__ __launch_bounds__(256) void suffix_main(
    float* __restrict__ dh, const float* __restrict__ fh,
    const float* __restrict__ Cp, float* __restrict__ Sp)
{
  const int g = blockIdx.x * 256 + threadIdx.x;   // (k,b,jh)
  const int k = g >> 14, bjh = g & 16383;
  const int b = bjh >> 9, jh = bjh & 511;
  float F = 1.f;
  for (int k2 = k + 1; k2 < 8; ++k2) F *= Cp[(k2 << 14) | bjh];
  float s0 = 0.f, s1 = 0.f, s2 = 0.f;
  for (int t = k * 16 + 15; t >= k * 16; --t) {
    size_t db = (size_t)t * 49152 + (size_t)b * 1536 + jh;
    float a0 = dh[db] * F, a1 = dh[db + 512] * F, a2 = dh[db + 1024] * F;
    dh[db] = a0; dh[db + 512] = a1; dh[db + 1024] = a2;
    s0 += a0; s1 += a1; s2 += a2;
    F *= fh[(size_t)t * 16384 + (size_t)b * 512 + jh];
  }
  size_t sb = ((size_t)k * 32 + b) * 1536 + jh;
  Sp[sb] = s0; Sp[sb + 512] = s1; Sp[sb + 1024] = s2;
}

__global__ __launch_bounds__(256) void evb_reduce(
    const float* __restrict__ Sp, float* __restrict__ evb)
{
  const int g = blockIdx.x * 256 + threadIdx.x;   // 0..49151
  float s = 0.f;
#pragma unroll
  for (int k = 0; k < 8; ++k) s += Sp[k * 49152 + g];
  evb[g] = s;
}

// ---------------------------------------------------------------------------
// bf16 hi/lo-split MFMA GEMM (proven in R7).  128x128 tile, BK=32.
// ---------------------------------------------------------------------------
__global__ __launch_bounds__(256, 2) void gemm_bf16s(
    const float* __restrict__ A, const float* __restrict__ B,
    float* __restrict__ C, const float* __restrict__ bias,
    int M, int N, int K,
    long long sAm, long long sAk, long long aBatch,
    long long sBn, long long sBk, long long bBatch,
    long long sCm1, long long sCm2, int M1, long long cBatch)
{
  __shared__ __align__(16) unsigned Ahi[128 * 20], Alo[128 * 20];
  __shared__ __align__(16) unsigned Bhi[128 * 20], Blo[128 * 20];

  const int tid  = threadIdx.x;
  const int lane = tid & 63;
  const int wave = tid >> 6;
  const int wm   = wave >> 1;
  const int wn   = wave & 1;
  const int cc   = lane & 15;
  const int kb   = lane >> 4;
  const long long z = blockIdx.z;
  const float* Ab = A + z * aBatch;
  const float* Bb = B + z * bBatch;
  const int m0 = blockIdx.y * 128, n0 = blockIdx.x * 128;

  f32x4 acc[4][4];
#pragma unroll
  for (int i = 0; i < 4; ++i)
#pragma unroll
    for (int j = 0; j < 4; ++j) acc[i][j] = (f32x4){0.f, 0.f, 0.f, 0.f};

  for (int k0 = 0; k0 < K; k0 += 32) {
    if (sAk == 1) {
      const int r = tid >> 1, half = tid & 1;
      const float* s = Ab + (long long)(m0 + r) * sAm + (k0 + half * 16);
      f32x4 v0 = *(const f32x4*)s;
      f32x4 v1 = *(const f32x4*)(s + 4);
      f32x4 v2 = *(const f32x4*)(s + 8);
      f32x4 v3 = *(const f32x4*)(s + 12);
      u32x4 h0, h1, l0, l1;
      HiLo p;
      p = packpair(v0[0], v0[1]); h0[0] = p.hi; l0[0] = p.lo;
      p = packpair(v0[2], v0[3]); h0[1] = p.hi; l0[1] = p.lo;
      p = packpair(v1[0], v1[1]); h0[2] = p.hi; l0[2] = p.lo;
      p = packpair(v1[2], v1[3]); h0[3] = p.hi; l0[3] = p.lo;
      p = packpair(v2[0], v2[1]); h1[0] = p.hi; l1[0] = p.lo;
      p = packpair(v2[2], v2[3]); h1[1] = p.hi; l1[1] = p.lo;
      p = packpair(v3[0], v3[1]); h1[2] = p.hi; l1[2] = p.lo;
      p = packpair(v3[2], v3[3]); h1[3] = p.hi; l1[3] = p.lo;
      const int o = r * 20 + half * 8;
      *(u32x4*)&Ahi[o] = h0;  *(u32x4*)&Ahi[o + 4] = h1;
      *(u32x4*)&Alo[o] = l0;  *(u32x4*)&Alo[o + 4] = l1;
    } else {
#pragma unroll
      for (int it = 0; it < 2; ++it) {
        const int kp = tid >> 4;
        const int mr = (tid & 15) * 4 + it * 64;
        const float* s0 = Ab + (long long)(k0 + 2 * kp) * sAk + (m0 + mr);
        f32x4 va = *(const f32x4*)s0;
        f32x4 vb = *(const f32x4*)(s0 + sAk);
#pragma unroll
        for (int q = 0; q < 4; ++q) {
          HiLo p = packpair(va[q], vb[q]);
          Ahi[(mr + q) * 20 + kp] = p.hi;
          Alo[(mr + q) * 20 + kp] = p.lo;
        }
      }
    }
    if (sBk == 1) {
      const int r = tid >> 1, half = tid & 1;
      const float* s = Bb + (long long)(n0 + r) * sBn + (k0 + half * 16);
      f32x4 v0 = *(const f32x4*)s;
      f32x4 v1 = *(const f32x4*)(s + 4);
      f32x4 v2 = *(const f32x4*)(s + 8);
      f32x4 v3 = *(const f32x4*)(s + 12);
      u32x4 h0, h1, l0, l1;
      HiLo p;
      p = packpair(v0[0], v0[1]); h0[0] = p.hi; l0[0] = p.lo;
      p = packpair(v0[2], v0[3]); h0[1] = p.hi; l0[1] = p.lo;
      p = packpair(v1[0], v1[1]); h0[2] = p.hi; l0[2] = p.lo;
      p = packpair(v1[2], v1[3]); h0[3] = p.hi; l0[3] = p.lo;
      p = packpair(v2[0], v2[1]); h1[0] = p.hi; l1[0] = p.lo;
      p = packpair(v2[2], v2[3]); h1[1] = p.hi; l1[1] = p.lo;
      p = packpair(v3[0], v3[1]); h1[2] = p.hi; l1[2] = p.lo;
      p = packpair(v3[2], v3[3]); h1[3] = p.hi; l1[3] = p.lo;
      const int o = r * 20 + half * 8;
      *(u32x4*)&Bhi[o] = h0;  *(u32x4*)&Bhi[o + 4] = h1;
      *(u32x4*)&Blo[o] = l0;  *(u32x4*)&Blo[o + 4] = l1;
    } else {
#pragma unroll
      for (int it = 0; it < 2; ++it) {
        const int kp = tid >> 4;
        const int nr = (tid & 15) * 4 + it * 64;
        const float* s0 = Bb + (long long)(k0 + 2 * kp) * sBk + (n0 + nr);
        f32x4 va = *(const f32x4*)s0;
        f32x4 vb = *(const f32x4*)(s0 + sBk);
#pragma unroll
        for (int q = 0; q < 4; ++q) {
          HiLo p = packpair(va[q], vb[q]);
          Bhi[(nr + q) * 20 + kp] = p.hi;
          Blo[(nr + q) * 20 + kp] = p.lo;
        }
      }
    }
    __syncthreads();

    short8 ah[4], al[4], bh[4], bl[4];
#pragma unroll
    for (int mi = 0; mi < 4; ++mi) {
      const int row = wm * 64 + mi * 16 + cc;
      ah[mi] = __builtin_bit_cast(short8, *(const u32x4*)&Ahi[row * 20 + kb * 4]);
      al[mi] = __builtin_bit_cast(short8, *(const u32x4*)&Alo[row * 20 + kb * 4]);
    }
#pragma unroll
    for (int ni = 0; ni < 4; ++ni) {
      const int row = wn * 64 + ni * 16 + cc;
      bh[ni] = __builtin_bit_cast(short8, *(const u32x4*)&Bhi[row * 20 + kb * 4]);
      bl[ni] = __builtin_bit_cast(short8, *(const u32x4*)&Blo[row * 20 + kb * 4]);
    }
#pragma unroll
    for (int mi = 0; mi < 4; ++mi)
#pragma unroll
      for (int ni = 0; ni < 4; ++ni) {
        acc[mi][ni] = __builtin_amdgcn_mfma_f32_16x16x32_bf16(ah[mi], bh[ni], acc[mi][ni], 0, 0, 0);
        acc[mi][ni] = __builtin_amdgcn_mfma_f32_16x16x32_bf16(ah[mi], bl[ni], acc[mi][ni], 0, 0, 0);
        acc[mi][ni] = __builtin_amdgcn_mfma_f32_16x16x32_bf16(al[mi], bh[ni], acc[mi][ni], 0, 0, 0);
      }
    __syncthreads();
  }

#pragma unroll
  for (int ni = 0; ni < 4; ++ni) {
    const int ng = n0 + wn * 64 + ni * 16 + cc;
    const float bv = bias ? bias[ng] : 0.f;
#pragma unroll
    for (int mi = 0; mi < 4; ++mi) {
#pragma unroll
      for (int r = 0; r < 4; ++r) {
        const int mg = m0 + wm * 64 + mi * 16 + kb * 4 + r;
        const long long crow = z * cBatch + (long long)(mg % M1) * sCm1 +
                               (long long)(mg / M1) * sCm2;
        C[crow + ng] = acc[mi][ni][r] + bv;
      }
    }
  }
}

// ---------------------------------------------------------------------------
// Small fp32 GEMM (tiny MLP/readout layers only).
// ---------------------------------------------------------------------------
template <int BM, int BN, int TM, int TN>
__global__ __launch_bounds__(256) void gemm_f32(
    const float* __restrict__ A, const float* __restrict__ B,
    float* __restrict__ C, const float* __restrict__ bias,
    int M, int N, int K,
    long long sAm, long long sAk, long long aBatch,
    long long sBn, long long sBk, long long bBatch,
    long long sCm1, long long sCm2, int M1, long long cBatch,
    int relu)
{
  constexpr int BK = 16;
  __shared__ float As[BK][BM + 4];
  __shared__ float Bs[BK][BN + 4];
  const int tid = threadIdx.x;
  const long long z = blockIdx.z;
  const float* Ab = A + z * aBatch;
  const float* Bb = B + z * bBatch;
  const int m0 = blockIdx.y * BM, n0 = blockIdx.x * BN;
  constexpr int tn_cnt = BN / TN;
  const int tm0 = (tid / tn_cnt) * TM;
  const int tn0 = (tid % tn_cnt) * TN;

  float acc[TM][TN];
#pragma unroll
  for (int i = 0; i < TM; ++i)
#pragma unroll
    for (int j = 0; j < TN; ++j) acc[i][j] = 0.f;

  for (int k0 = 0; k0 < K; k0 += BK) {
    if (sAk == 1) {
      for (int m = tid >> 2; m < BM; m += 64) {
        const int kq = (tid & 3) * 4;
        f32x4 v = {0.f, 0.f, 0.f, 0.f};
        if (m0 + m < M) v = *(const f32x4*)(Ab + (long long)(m0 + m) * sAm + (k0 + kq));
        As[kq + 0][m] = v[0]; As[kq + 1][m] = v[1];
        As[kq + 2][m] = v[2]; As[kq + 3][m] = v[3];
      }
    } else {
      constexpr int mq_cnt = BM / 4;
      for (int kk = tid / mq_cnt; kk < BK; kk += 256 / mq_cnt) {
        const int mq = (tid % mq_cnt) * 4;
        f32x4 v = {0.f, 0.f, 0.f, 0.f};
        if (m0 + mq < M) v = *(const f32x4*)(Ab + (long long)(k0 + kk) * sAk + (m0 + mq));
        *(f32x4*)&As[kk][mq] = v;
      }
    }
    if (sBk == 1) {
      for (int n = tid >> 2; n < BN; n += 64) {
        const int kq = (tid & 3) * 4;
        f32x4 v = {0.f, 0.f, 0.f, 0.f};
        if (n0 + n < N) v = *(const f32x4*)(Bb + (long long)(n0 + n) * sBn + (k0 + kq));
        Bs[kq + 0][n] = v[0]; Bs[kq + 1][n] = v[1];
        Bs[kq + 2][n] = v[2]; Bs[kq + 3][n] = v[3];
      }
    } else {
      constexpr int nq_cnt = BN / 4;
      for (int kk = tid / nq_cnt; kk < BK; kk += 256 / nq_cnt) {
        const int nq = (tid % nq_cnt) * 4;
        f32x4 v = {0.f, 0.f, 0.f, 0.f};
        if (n0 + nq < N) v = *(const f32x4*)(Bb + (long long)(k0 + kk) * sBk + (n0 + nq));
        *(f32x4*)&Bs[kk][nq] = v;
      }
    }
    __syncthreads();

#pragma unroll
    for (int kk = 0; kk < BK; ++kk) {
      float a[TM], bb[TN];
#pragma unroll
      for (int i = 0; i < TM; ++i) a[i] = As[kk][tm0 + i];
#pragma unroll
      for (int j = 0; j < TN; ++j) bb[j] = Bs[kk][tn0 + j];
#pragma unroll
      for (int i = 0; i < TM; ++i)
#pragma unroll
        for (int j = 0; j < TN; ++j) acc[i][j] += a[i] * bb[j];
    }
    __syncthreads();
  }

#pragma unroll
  for (int i = 0; i < TM; ++i) {
    const int mg = m0 + tm0 + i;
    if (mg >= M) continue;
    const long long crow = z * cBatch + (long long)(mg % M1) * sCm1 +
                           (long long)(mg / M1) * sCm2;
#pragma unroll
    for (int j = 0; j < TN; ++j) {
      const int ng = n0 + tn0 + j;
      if (ng >= N) continue;
      float v = acc[i][j];
      if (bias) v += bias[ng];
      if (relu) v = fmaxf(v, 0.f);
      C[crow + ng] = v;
    }
  }
}

// ---------------------------------------------------------------------------
extern "C" void kernel_launch(void* const* d_in, const int* in_sizes, int n_in,
                              void* d_out, int out_size, void* d_ws, size_t ws_size,
                              hipStream_t stream) {
  const float* x   = (const float*)d_in[0];
  const float* Wih = (const float*)d_in[1];
  const float* Whh = (const float*)d_in[2];
  const float* bl  = (const float*)d_in[3];
  const float* Wd  = (const float*)d_in[4];
  const float* bd  = (const float*)d_in[5];
  const float* Ws1 = (const float*)d_in[6];
  const float* bs1 = (const float*)d_in[7];
  const float* Ws2 = (const float*)d_in[8];
  const float* bs2 = (const float*)d_in[9];
  const float* Ws3 = (const float*)d_in[10];
  const float* bs3 = (const float*)d_in[11];
  const float* Ws4 = (const float*)d_in[12];
  const float* bs4 = (const float*)d_in[13];

  float* out = (float*)d_out;
  float* ws  = (float*)d_ws;

  // d_out layout (floats)
  const long long OP = 0, OS = 320, OEX = 16704, OEH = 12599616, OEB = 37765440;

  // scratch inside ev_h output region (dead before final ev_h GEMM writes it)
  float* XW = out + OEH;                              // [128][32][2048]
  float* fh = out + OEH + 8388608;                    // [128][32][512]
  unsigned* Hp = (unsigned*)(out + OEH + 10485760);   // [129][32][256] hi slices
  float* Cp = out + OEH + 11542528;                   // [8][32][512]
  float* Sp = out + OEH + 11673600;                   // [8][32][1536]

  // ws scratch
  float* dh = ws;                       // [128][32][1536]  d -> A in place
  float* Hf = ws + 6291456;             // [129][32][512] fp32
  float* z1 = ws + 8404992;             // [32][512]
  float* z2 = ws + 8421376;             // [32][256]
  float* z3 = ws + 8429568;             // [32][128]

  // Hp pre-filled with the sentinel byte pattern (0x7F7F7F7F impossible as
  // packed bf16 of h in (-1,1))
  hipMemsetAsync(Hp, 0x7F, 129ull * 32 * 256 * sizeof(unsigned), stream);
  hipMemsetAsync(Hf, 0, 16384 * sizeof(float), stream);    // H[0] = 0

  dim3 blk(256);

  // K1 (MFMA): XW[t][b][j] = x @ Wih^T + b_lstm   (M=4096, N=2048, K=256)
  gemm_bf16s<<<dim3(16, 32, 1), blk, 0, stream>>>(
      x, Wih, XW, bl, 4096, 2048, 256,
      256, 1, 0,            // A: x[m][k], k-contiguous
      256, 1, 0,            // B: Wih[n][k], k-contiguous
      65536, 2048, 128, 0); // C: XW[t=m%128][b=m/128][n]

  // K2: persistent recurrence (EXACT R10 kernel: 32 WGs x 512, sentinel)
  lstm_rec<<<dim3(32), dim3(512), 0, stream>>>(Whh, XW, Hp, Hf, dh, fh);

  // K3: 8-chunk suffix products, A in place, ev_b
  suffix_pre<<<dim3(512), blk, 0, stream>>>(fh, Cp);
  suffix_main<<<dim3(512), blk, 0, stream>>>(dh, fh, Cp, Sp);
  evb_reduce<<<dim3(192), blk, 0, stream>>>(Sp, out + OEB);

  // MLP + readout on last = Hf[128] (tiny, fp32)
  const float* hlast = Hf + 2097152;
  gemm_f32<32, 32, 2, 2><<<dim3(16, 1, 1), blk, 0, stream>>>(
      hlast, Ws1, z1, bs1, 32, 512, 512, 512, 1, 0, 512, 1, 0, 512, 0, 32, 0, 1);
  gemm_f32<32, 32, 2, 2><<<dim3(8, 1, 1), blk, 0, stream>>>(
      z1, Ws2, z2, bs2, 32, 256, 512, 512, 1, 0, 512, 1, 0, 256, 0, 32, 0, 1);
  gemm_f32<32, 32, 2, 2><<<dim3(4, 1, 1), blk, 0, stream>>>(
      z2, Ws3, z3, bs3, 32, 128, 256, 256, 1, 0, 256, 1, 0, 128, 0, 32, 0, 1);
  gemm_f32<32, 32, 2, 2><<<dim3(16, 1, 1), blk, 0, stream>>>(
      z3, Ws4, out + OS, bs4, 32, 512, 128, 128, 1, 0, 128, 1, 0, 512, 0, 32, 0, 0);
  gemm_f32<32, 32, 2, 2><<<dim3(1, 1, 1), blk, 0, stream>>>(
      hlast, Wd, out + OP, bd, 32, 10, 512, 512, 1, 0, 512, 1, 0, 10, 0, 32, 0, 0);

  // K4 (MFMA): ev_x[b][j][i] = sum_t A[t][b][j] * x[b][t][i]
  gemm_bf16s<<<dim3(2, 12, 32), blk, 0, stream>>>(
      dh, x, out + OEX, nullptr, 1536, 256, 128,
      1, 49152, 1536,       // A: dh[t][b][j], m=j contiguous
      1, 256, 32768,        // B: x[b][t][i], n=i contiguous
      256, 0, 1536, 393216);

  // K5 (MFMA): ev_h[b][j][k] = sum_t A[t][b][j] * h_{t-1}[b][k]
  // (runs last: overwrites XW/fh/Hp/Cp/Sp scratch living in the ev_h region)
  gemm_bf16s<<<dim3(4, 12, 32), blk, 0, stream>>>(
      dh, Hf, out + OEH, nullptr, 1536, 512, 128,
      1, 49152, 1536,       // A: dh[t][b][j]
      1, 16384, 512,        // B: Hf[t][b][k], n=k contiguous
      512, 0, 1536, 786432);
}

// Round 15
// 631.767 us; speedup vs baseline: 1.2281x; 1.0054x over previous
//
#include <hip/hip_runtime.h>

// ---------------------------------------------------------------------------
// EPROP3_LSTM: e-prop LSTM fwd.  Reformulation:
//   ev_x[b,j,k] = sum_t A_t[b,j] * x_t[b,k],   A_t = d_t * F_t, F_t = prod_{s>t} f_s
//   ev_h[b,j,k] = sum_t A_t[b,j] * h_{t-1}[b,k]
//   ev_b[b,j]   = sum_t A_t[b,j]
// => sequential LSTM recurrence + suffix scan + batched GEMMs (K=T=128).
//
// Round-15: R14 + K1 demoted to a 2-term bf16 split (x rounded to bf16;
// error ~3e-4 << current margin).  gemm_bf16s templated on NTERMS so the
// A-lo staging and third MFMA are compile-time dead for K1.  Recurrence =
// exact R10 kernel (measured floor).  K4/K5 stay 3-term.
// ---------------------------------------------------------------------------

typedef __attribute__((ext_vector_type(8))) short short8;
typedef __attribute__((ext_vector_type(4))) float f32x4;
typedef __attribute__((ext_vector_type(4))) unsigned u32x4;

#define DEV static __device__ __forceinline__

DEV unsigned f2bf(float x) {
  union { float f; unsigned u; } v; v.f = x;
  return (v.u + 0x7fffu + ((v.u >> 16) & 1u)) >> 16;
}
DEV float bf2f(unsigned b) {
  union { float f; unsigned u; } v; v.u = b << 16;
  return v.f;
}
struct HiLo { unsigned hi, lo; };
// pack two floats into (hi-bf16 pair, lo-bf16 pair)
DEV HiLo packpair(float a, float b) {
  unsigned ha = f2bf(a), hb = f2bf(b);
  unsigned la = f2bf(a - bf2f(ha)), lb = f2bf(b - bf2f(hb));
  HiLo r; r.hi = ha | (hb << 16); r.lo = la | (lb << 16);
  return r;
}

#define SENT 0x7F7F7F7Fu

// ---------------------------------------------------------------------------
// Persistent LSTM recurrence (EXACT R10 kernel, best measured).
// 32 WGs x 512 threads.  WG wg owns units [wg*16, wg*16+16) -> 64 gate rows.
// Whh slice in registers as bf16 hi/lo MFMA B-fragments; hi-only h exchange;
// sentinel dataflow sync.
// ---------------------------------------------------------------------------
__global__ __launch_bounds__(512, 1) void lstm_rec(
    const float* __restrict__ Whh,        // [2048][512]
    const float* __restrict__ XW,         // [128][32][2048]  x@Wih^T + b
    unsigned* __restrict__ Hp,            // [129][32][256] hi slices, SENT-filled
    float* __restrict__ Hf,               // [129][32][512] fp32 (private)
    float* __restrict__ dh,               // [128][32][1536] (private)
    float* __restrict__ fh)               // [128][32][512] (private)
{
  const int wg   = blockIdx.x;            // 0..31
  const int tid  = threadIdx.x;           // 0..511
  const int lane = tid & 63;
  const int wave = tid >> 6;              // 0..7
  const int tM   = wave & 1;              // batch-tile (0..1)
  const int tN   = wave >> 1;             // row-tile   (0..3)

  __shared__ __align__(16) unsigned Ldh[32 * 256];  // hi bf16 pairs [be][kp]
  __shared__ float gl[32][68];                      // gates tile [b][r]

  const int cc = lane & 15;
  const int kb = lane >> 4;

  // ---- load Whh B-fragments once (hi/lo bf16 split) ----
  const int rloc  = tN * 16 + cc;                              // local row 0..63
  const int jglob = (rloc >> 4) * 512 + wg * 16 + (rloc & 15); // global gate row
  short8 whi[16], wlo[16];
#pragma unroll
  for (int s = 0; s < 16; ++s) {
    const float* wp = Whh + (size_t)jglob * 512 + s * 32 + kb * 8;
    f32x4 w0 = *(const f32x4*)wp;
    f32x4 w1 = *(const f32x4*)(wp + 4);
    short8 hi, lo;
#pragma unroll
    for (int j = 0; j < 4; ++j) {
      unsigned h0 = f2bf(w0[j]);
      hi[j] = (short)h0;  lo[j] = (short)f2bf(w0[j] - bf2f(h0));
      unsigned h1 = f2bf(w1[j]);
      hi[4 + j] = (short)h1;  lo[4 + j] = (short)f2bf(w1[j] - bf2f(h1));
    }
    whi[s] = hi; wlo[s] = lo;
  }

  // MFMA A-fragment LDS read base (dword index), XOR-swizzled
  const int bA = tM * 16 + cc;
  const int mz = bA & 7;
  const unsigned rbase = (unsigned)(bA * 256 + ((kb ^ (mz & 3)) << 2) + ((mz >> 2) << 4));

  // staging write mapping (per lane): row beW, chunk c ^ (beW&7)
  const int beW = lane >> 1;
  const int swz = beW & 7;

  const int be = tid >> 4;          // elementwise: batch 0..31
  const int jo = tid & 15;          // elementwise: local hidden unit 0..15
  const int jh = wg * 16 + jo;      // global hidden unit
  float c_reg = 0.f;

  for (int t = 0; t < 128; ++t) {
    // ---- XW prefetch (plain loads; complete under the poll) ----
    const float* xwp = XW + (size_t)t * 65536 + (size_t)be * 2048 + wg * 16 + jo;
    float xwi = xwp[0], xwf = xwp[512], xwg = xwp[1024], xwo = xwp[1536];

    if (t > 0) {
      // ---- poll the DATA of this wave's 4 producers until sentinel-free ----
      const unsigned* sp = Hp + ((size_t)t * 32 + wave * 4) * 256 + lane * 4;
      u32x4 h0, h1, h2, h3;
      for (;;) {
#define SLICE_LOAD(dst, addr)                                          \
        asm volatile("global_load_dwordx4 %0, %1, off sc0 sc1"         \
                     : "=&v"(dst) : "v"(addr) : "memory")
        SLICE_LOAD(h0, sp);
        SLICE_LOAD(h1, sp + 256);
        SLICE_LOAD(h2, sp + 512);
        SLICE_LOAD(h3, sp + 768);
#undef SLICE_LOAD
        asm volatile("s_waitcnt vmcnt(0)" ::: "memory");
        // rule #18: fence the register-only sentinel compares BELOW the wait
        __builtin_amdgcn_sched_barrier(0);
        unsigned bad = (unsigned)((h0[0] == SENT) | (h0[1] == SENT) |
                                  (h0[2] == SENT) | (h0[3] == SENT) |
                                  (h1[0] == SENT) | (h1[1] == SENT) |
                                  (h1[2] == SENT) | (h1[3] == SENT) |
                                  (h2[0] == SENT) | (h2[1] == SENT) |
                                  (h2[2] == SENT) | (h2[3] == SENT) |
                                  (h3[0] == SENT) | (h3[1] == SENT) |
                                  (h3[2] == SENT) | (h3[3] == SENT));
        if (!__any((int)bad)) break;
        __builtin_amdgcn_s_sleep(1);
      }
      __builtin_amdgcn_sched_barrier(0);

      // ---- scatter to swizzled LDS tile (b128 writes) ----
      const int c0 = wave * 8 + (lane & 1);   // producer (wave*4+i) -> chunk c0+2i
      const unsigned wb = (unsigned)(beW * 256);
      *(u32x4*)&Ldh[wb + (((c0 + 0) ^ swz) << 2)] = h0;
      *(u32x4*)&Ldh[wb + (((c0 + 2) ^ swz) << 2)] = h1;
      *(u32x4*)&Ldh[wb + (((c0 + 4) ^ swz) << 2)] = h2;
      *(u32x4*)&Ldh[wb + (((c0 + 6) ^ swz) << 2)] = h3;
    }
    __syncthreads();

    // ---- MFMA: gates_tile = H[t] @ Whh_slice^T (2 independent chains) ----
    f32x4 acc;
    {
      f32x4 a0 = {0.f, 0.f, 0.f, 0.f}, a1 = a0;
      if (t > 0) {
#pragma unroll
        for (int s = 0; s < 16; ++s) {
          const unsigned idx = rbase ^ (unsigned)(s << 4);
          short8 ah = __builtin_bit_cast(short8, *(const u32x4*)&Ldh[idx]);
          a0 = __builtin_amdgcn_mfma_f32_16x16x32_bf16(ah, whi[s], a0, 0, 0, 0);
          a1 = __builtin_amdgcn_mfma_f32_16x16x32_bf16(ah, wlo[s], a1, 0, 0, 0);
        }
      }
      acc = a0 + a1;
    }
    // D layout: row m = 16*tM + 4*(lane>>4)+r (batch), col n = 16*tN + (lane&15)
#pragma unroll
    for (int r = 0; r < 4; ++r)
      gl[tM * 16 + kb * 4 + r][tN * 16 + cc] = acc[r];
    __syncthreads();

    // ---- elementwise LSTM update: thread = (batch be, unit jo) ----
    {
      float pi = xwi + gl[be][jo];
      float pf = xwf + gl[be][16 + jo];
      float pg = xwg + gl[be][32 + jo];
      float po = xwo + gl[be][48 + jo];
      float ig = 1.f / (1.f + expf(-pi));
      float fg = 1.f / (1.f + expf(-pf));
      float gg = tanhf(pg);
      float og = 1.f / (1.f + expf(-po));
      float di = gg * ig * (1.f - ig);
      float df = c_reg * fg * (1.f - fg);     // uses c_{t-1}
      float dg = ig * (1.f - gg * gg);
      c_reg = fg * c_reg + ig * gg;
      float hn = og * tanhf(c_reg);

      // pack bf16 hi pair with neighbor lane; slice store FIRST (critical)
      unsigned hh = f2bf(hn);
      unsigned hh_nb = (unsigned)__shfl_xor((int)hh, 1);
      if (!(tid & 1)) {
        unsigned stv = hh | (hh_nb << 16);
        size_t sa = ((size_t)(t + 1) * 32 + wg) * 256 + (tid >> 1);
        __hip_atomic_store(&Hp[sa], stv, __ATOMIC_RELAXED, __HIP_MEMORY_SCOPE_AGENT);
      }

      // private stores AFTER the slice store (off the critical path)
      Hf[(size_t)(t + 1) * 16384 + (size_t)be * 512 + jh] = hn;
      size_t db = (size_t)t * 49152 + (size_t)be * 1536 + jh;
      dh[db] = di; dh[db + 512] = df; dh[db + 1024] = dg;
      fh[(size_t)t * 16384 + (size_t)be * 512 + jh] = fg;
    }
  }
}

// ---------------------------------------------------------------------------
// Suffix scan, 8-way chunked over t (chunk = 16 steps).
// ---------------------------------------------------------------------------
__global__ __launch_bounds__(256) void suffix_pre(
    const float* __restrict__ fh, float* __restrict__ Cp)
{
  const int g = blockIdx.x * 256 + threadIdx.x;   // 0..131071 = (k,b,jh)
  const int k = g >> 14, bjh = g & 16383;
  const int b = bjh >> 9, jh = bjh & 511;
  float P = 1.f;
  for (int t = k * 16; t < k * 16 + 16; ++t)
    P *= fh[(size_t)t * 16384 + (size_t)b * 512 + jh];
  Cp[g] = P;
}

__global__ __launch_bounds__(256) void suffix_main(
    float* __restrict__ dh, const float* __restrict__ fh,
    const float* __restrict__ Cp, float* __restrict__ Sp)
{
  const int g = blockIdx.x * 256 + threadIdx.x;   // (k,b,jh)
  const int k = g >> 14, bjh = g & 16383;
  const int b = bjh >> 9, jh = bjh & 511;
  float F = 1.f;
  for (int k2 = k + 1; k2 < 8; ++k2) F *= Cp[(k2 << 14) | bjh];
  float s0 = 0.f, s1 = 0.f, s2 = 0.f;
  for (int t = k * 16 + 15; t >= k * 16; --t) {
    size_t db = (size_t)t * 49152 + (size_t)b * 1536 + jh;
    float a0 = dh[db] * F, a1 = dh[db + 512] * F, a2 = dh[db + 1024] * F;
    dh[db] = a0; dh[db + 512] = a1; dh[db + 1024] = a2;
    s0 += a0; s1 += a1; s2 += a2;
    F *= fh[(size_t)t * 16384 + (size_t)b * 512 + jh];
  }
  size_t sb = ((size_t)k * 32 + b) * 1536 + jh;
  Sp[sb] = s0; Sp[sb + 512] = s1; Sp[sb + 1024] = s2;
}

__global__ __launch_bounds__(256) void evb_reduce(
    const float* __restrict__ Sp, float* __restrict__ evb)
{
  const int g = blockIdx.x * 256 + threadIdx.x;   // 0..49151
  float s = 0.f;
#pragma unroll
  for (int k = 0; k < 8; ++k) s += Sp[k * 49152 + g];
  evb[g] = s;
}

// ---------------------------------------------------------------------------
// bf16 split MFMA GEMM (proven in R7).  128x128 tile, BK=32.
// NTERMS=3: Ah*Bh + Ah*Bl + Al*Bh (~fp32).  NTERMS=2: Ah*Bh + Ah*Bl
// (A rounded to bf16; A-lo staging compile-time dead).
// ---------------------------------------------------------------------------
template <int NTERMS>
__global__ __launch_bounds__(256, 2) void gemm_bf16s(
    const float* __restrict__ A, const float* __restrict__ B,
    float* __restrict__ C, const float* __restrict__ bias,
    int M, int N, int K,
    long long sAm, long long sAk, long long aBatch,
    long long sBn, long long sBk, long long bBatch,
    long long sCm1, long long sCm2, int M1, long long cBatch)
{
  __shared__ __align__(16) unsigned Ahi[128 * 20];
  __shared__ __align__(16) unsigned Alo[NTERMS == 3 ? 128 * 20 : 4];
  __shared__ __align__(16) unsigned Bhi[128 * 20], Blo[128 * 20];

  const int tid  = threadIdx.x;
  const int lane = tid & 63;
  const int wave = tid >> 6;
  const int wm   = wave >> 1;
  const int wn   = wave & 1;
  const int cc   = lane & 15;
  const int kb   = lane >> 4;
  const long long z = blockIdx.z;
  const float* Ab = A + z * aBatch;
  const float* Bb = B + z * bBatch;
  const int m0 = blockIdx.y * 128, n0 = blockIdx.x * 128;

  f32x4 acc[4][4];
#pragma unroll
  for (int i = 0; i < 4; ++i)
#pragma unroll
    for (int j = 0; j < 4; ++j) acc[i][j] = (f32x4){0.f, 0.f, 0.f, 0.f};

  for (int k0 = 0; k0 < K; k0 += 32) {
    if (sAk == 1) {
      const int r = tid >> 1, half = tid & 1;
      const float* s = Ab + (long long)(m0 + r) * sAm + (k0 + half * 16);
      f32x4 v0 = *(const f32x4*)s;
      f32x4 v1 = *(const f32x4*)(s + 4);
      f32x4 v2 = *(const f32x4*)(s + 8);
      f32x4 v3 = *(const f32x4*)(s + 12);
      u32x4 h0, h1, l0, l1;
      HiLo p;
      p = packpair(v0[0], v0[1]); h0[0] = p.hi; l0[0] = p.lo;
      p = packpair(v0[2], v0[3]); h0[1] = p.hi; l0[1] = p.lo;
      p = packpair(v1[0], v1[1]); h0[2] = p.hi; l0[2] = p.lo;
      p = packpair(v1[2], v1[3]); h0[3] = p.hi; l0[3] = p.lo;
      p = packpair(v2[0], v2[1]); h1[0] = p.hi; l1[0] = p.lo;
      p = packpair(v2[2], v2[3]); h1[1] = p.hi; l1[1] = p.lo;
      p = packpair(v3[0], v3[1]); h1[2] = p.hi; l1[2] = p.lo;
      p = packpair(v3[2], v3[3]); h1[3] = p.hi; l1[3] = p.lo;
      const int o = r * 20 + half * 8;
      *(u32x4*)&Ahi[o] = h0;  *(u32x4*)&Ahi[o + 4] = h1;
      if (NTERMS == 3) {
        *(u32x4*)&Alo[o] = l0;  *(u32x4*)&Alo[o + 4] = l1;
      }
    } else {
#pragma unroll
      for (int it = 0; it < 2; ++it) {
        const int kp = tid >> 4;
        const int mr = (tid & 15) * 4 + it * 64;
        const float* s0 = Ab + (long long)(k0 + 2 * kp) * sAk + (m0 + mr);
        f32x4 va = *(const f32x4*)s0;
        f32x4 vb = *(const f32x4*)(s0 + sAk);
#pragma unroll
        for (int q = 0; q < 4; ++q) {
          HiLo p = packpair(va[q], vb[q]);
          Ahi[(mr + q) * 20 + kp] = p.hi;
          if (NTERMS == 3) Alo[(mr + q) * 20 + kp] = p.lo;
        }
      }
    }
    if (sBk == 1) {
      const int r = tid >> 1, half = tid & 1;
      const float* s = Bb + (long long)(n0 + r) * sBn + (k0 + half * 16);
      f32x4 v0 = *(const f32x4*)s;
      f32x4 v1 = *(const f32x4*)(s + 4);
      f32x4 v2 = *(const f32x4*)(s + 8);
      f32x4 v3 = *(const f32x4*)(s + 12);
      u32x4 h0, h1, l0, l1;
      HiLo p;
      p = packpair(v0[0], v0[1]); h0[0] = p.hi; l0[0] = p.lo;
      p = packpair(v0[2], v0[3]); h0[1] = p.hi; l0[1] = p.lo;
      p = packpair(v1[0], v1[1]); h0[2] = p.hi; l0[2] = p.lo;
      p = packpair(v1[2], v1[3]); h0[3] = p.hi; l0[3] = p.lo;
      p = packpair(v2[0], v2[1]); h1[0] = p.hi; l1[0] = p.lo;
      p = packpair(v2[2], v2[3]); h1[1] = p.hi; l1[1] = p.lo;
      p = packpair(v3[0], v3[1]); h1[2] = p.hi; l1[2] = p.lo;
      p = packpair(v3[2], v3[3]); h1[3] = p.hi; l1[3] = p.lo;
      const int o = r * 20 + half * 8;
      *(u32x4*)&Bhi[o] = h0;  *(u32x4*)&Bhi[o + 4] = h1;
      *(u32x4*)&Blo[o] = l0;  *(u32x4*)&Blo[o + 4] = l1;
    } else {
#pragma unroll
      for (int it = 0; it < 2; ++it) {
        const int kp = tid >> 4;
        const int nr = (tid & 15) * 4 + it * 64;
        const float* s0 = Bb + (long long)(k0 + 2 * kp) * sBk + (n0 + nr);
        f32x4 va = *(const f32x4*)s0;
        f32x4 vb = *(const f32x4*)(s0 + sBk);
#pragma unroll
        for (int q = 0; q < 4; ++q) {
          HiLo p = packpair(va[q], vb[q]);
          Bhi[(nr + q) * 20 + kp] = p.hi;
          Blo[(nr + q) * 20 + kp] = p.lo;
        }
      }
    }
    __syncthreads();

    short8 ah[4], al[4], bh[4], bl[4];
#pragma unroll
    for (int mi = 0; mi < 4; ++mi) {
      const int row = wm * 64 + mi * 16 + cc;
      ah[mi] = __builtin_bit_cast(short8, *(const u32x4*)&Ahi[row * 20 + kb * 4]);
      if (NTERMS == 3)
        al[mi] = __builtin_bit_cast(short8, *(const u32x4*)&Alo[row * 20 + kb * 4]);
    }
#pragma unroll
    for (int ni = 0; ni < 4; ++ni) {
      const int row = wn * 64 + ni * 16 + cc;
      bh[ni] = __builtin_bit_cast(short8, *(const u32x4*)&Bhi[row * 20 + kb * 4]);
      bl[ni] = __builtin_bit_cast(short8, *(const u32x4*)&Blo[row * 20 + kb * 4]);
    }
#pragma unroll
    for (int mi = 0; mi < 4; ++mi)
#pragma unroll
      for (int ni = 0; ni < 4; ++ni) {
        acc[mi][ni] = __builtin_amdgcn_mfma_f32_16x16x32_bf16(ah[mi], bh[ni], acc[mi][ni], 0, 0, 0);
        acc[mi][ni] = __builtin_amdgcn_mfma_f32_16x16x32_bf16(ah[mi], bl[ni], acc[mi][ni], 0, 0, 0);
        if (NTERMS == 3)
          acc[mi][ni] = __builtin_amdgcn_mfma_f32_16x16x32_bf16(al[mi], bh[ni], acc[mi][ni], 0, 0, 0);
      }
    __syncthreads();
  }

#pragma unroll
  for (int ni = 0; ni < 4; ++ni) {
    const int ng = n0 + wn * 64 + ni * 16 + cc;
    const float bv = bias ? bias[ng] : 0.f;
#pragma unroll
    for (int mi = 0; mi < 4; ++mi) {
#pragma unroll
      for (int r = 0; r < 4; ++r) {
        const int mg = m0 + wm * 64 + mi * 16 + kb * 4 + r;
        const long long crow = z * cBatch + (long long)(mg % M1) * sCm1 +
                               (long long)(mg / M1) * sCm2;
        C[crow + ng] = acc[mi][ni][r] + bv;
      }
    }
  }
}

// ---------------------------------------------------------------------------
// Small fp32 GEMM (tiny MLP/readout layers only).
// ---------------------------------------------------------------------------
template <int BM, int BN, int TM, int TN>
__global__ __launch_bounds__(256) void gemm_f32(
    const float* __restrict__ A, const float* __restrict__ B,
    float* __restrict__ C, const float* __restrict__ bias,
    int M, int N, int K,
    long long sAm, long long sAk, long long aBatch,
    long long sBn, long long sBk, long long bBatch,
    long long sCm1, long long sCm2, int M1, long long cBatch,
    int relu)
{
  constexpr int BK = 16;
  __shared__ float As[BK][BM + 4];
  __shared__ float Bs[BK][BN + 4];
  const int tid = threadIdx.x;
  const long long z = blockIdx.z;
  const float* Ab = A + z * aBatch;
  const float* Bb = B + z * bBatch;
  const int m0 = blockIdx.y * BM, n0 = blockIdx.x * BN;
  constexpr int tn_cnt = BN / TN;
  const int tm0 = (tid / tn_cnt) * TM;
  const int tn0 = (tid % tn_cnt) * TN;

  float acc[TM][TN];
#pragma unroll
  for (int i = 0; i < TM; ++i)
#pragma unroll
    for (int j = 0; j < TN; ++j) acc[i][j] = 0.f;

  for (int k0 = 0; k0 < K; k0 += BK) {
    if (sAk == 1) {
      for (int m = tid >> 2; m < BM; m += 64) {
        const int kq = (tid & 3) * 4;
        f32x4 v = {0.f, 0.f, 0.f, 0.f};
        if (m0 + m < M) v = *(const f32x4*)(Ab + (long long)(m0 + m) * sAm + (k0 + kq));
        As[kq + 0][m] = v[0]; As[kq + 1][m] = v[1];
        As[kq + 2][m] = v[2]; As[kq + 3][m] = v[3];
      }
    } else {
      constexpr int mq_cnt = BM / 4;
      for (int kk = tid / mq_cnt; kk < BK; kk += 256 / mq_cnt) {
        const int mq = (tid % mq_cnt) * 4;
        f32x4 v = {0.f, 0.f, 0.f, 0.f};
        if (m0 + mq < M) v = *(const f32x4*)(Ab + (long long)(k0 + kk) * sAk + (m0 + mq));
        *(f32x4*)&As[kk][mq] = v;
      }
    }
    if (sBk == 1) {
      for (int n = tid >> 2; n < BN; n += 64) {
        const int kq = (tid & 3) * 4;
        f32x4 v = {0.f, 0.f, 0.f, 0.f};
        if (n0 + n < N) v = *(const f32x4*)(Bb + (long long)(n0 + n) * sBn + (k0 + kq));
        Bs[kq + 0][n] = v[0]; Bs[kq + 1][n] = v[1];
        Bs[kq + 2][n] = v[2]; Bs[kq + 3][n] = v[3];
      }
    } else {
      constexpr int nq_cnt = BN / 4;
      for (int kk = tid / nq_cnt; kk < BK; kk += 256 / nq_cnt) {
        const int nq = (tid % nq_cnt) * 4;
        f32x4 v = {0.f, 0.f, 0.f, 0.f};
        if (n0 + nq < N) v = *(const f32x4*)(Bb + (long long)(k0 + kk) * sBk + (n0 + nq));
        *(f32x4*)&Bs[kk][nq] = v;
      }
    }
    __syncthreads();

#pragma unroll
    for (int kk = 0; kk < BK; ++kk) {
      float a[TM], bb[TN];
#pragma unroll
      for (int i = 0; i < TM; ++i) a[i] = As[kk][tm0 + i];
#pragma unroll
      for (int j = 0; j < TN; ++j) bb[j] = Bs[kk][tn0 + j];
#pragma unroll
      for (int i = 0; i < TM; ++i)
#pragma unroll
        for (int j = 0; j < TN; ++j) acc[i][j] += a[i] * bb[j];
    }
    __syncthreads();
  }

#pragma unroll
  for (int i = 0; i < TM; ++i) {
    const int mg = m0 + tm0 + i;
    if (mg >= M) continue;
    const long long crow = z * cBatch + (long long)(mg % M1) * sCm1 +
                           (long long)(mg / M1) * sCm2;
#pragma unroll
    for (int j = 0; j < TN; ++j) {
      const int ng = n0 + tn0 + j;
      if (ng >= N) continue;
      float v = acc[i][j];
      if (bias) v += bias[ng];
      if (relu) v = fmaxf(v, 0.f);
      C[crow + ng] = v;
    }
  }
}

// ---------------------------------------------------------------------------
extern "C" void kernel_launch(void* const* d_in, const int* in_sizes, int n_in,
                              void* d_out, int out_size, void* d_ws, size_t ws_size,
                              hipStream_t stream) {
  const float* x   = (const float*)d_in[0];
  const float* Wih = (const float*)d_in[1];
  const float* Whh = (const float*)d_in[2];
  const float* bl  = (const float*)d_in[3];
  const float* Wd  = (const float*)d_in[4];
  const float* bd  = (const float*)d_in[5];
  const float* Ws1 = (const float*)d_in[6];
  const float* bs1 = (const float*)d_in[7];
  const float* Ws2 = (const float*)d_in[8];
  const float* bs2 = (const float*)d_in[9];
  const float* Ws3 = (const float*)d_in[10];
  const float* bs3 = (const float*)d_in[11];
  const float* Ws4 = (const float*)d_in[12];
  const float* bs4 = (const float*)d_in[13];

  float* out = (float*)d_out;
  float* ws  = (float*)d_ws;

  // d_out layout (floats)
  const long long OP = 0, OS = 320, OEX = 16704, OEH = 12599616, OEB = 37765440;

  // scratch inside ev_h output region (dead before final ev_h GEMM writes it)
  float* XW = out + OEH;                              // [128][32][2048]
  float* fh = out + OEH + 8388608;                    // [128][32][512]
  unsigned* Hp = (unsigned*)(out + OEH + 10485760);   // [129][32][256] hi slices
  float* Cp = out + OEH + 11542528;                   // [8][32][512]
  float* Sp = out + OEH + 11673600;                   // [8][32][1536]

  // ws scratch
  float* dh = ws;                       // [128][32][1536]  d -> A in place
  float* Hf = ws + 6291456;             // [129][32][512] fp32
  float* z1 = ws + 8404992;             // [32][512]
  float* z2 = ws + 8421376;             // [32][256]
  float* z3 = ws + 8429568;             // [32][128]

  // Hp pre-filled with the sentinel byte pattern (0x7F7F7F7F impossible as
  // packed bf16 of h in (-1,1))
  hipMemsetAsync(Hp, 0x7F, 129ull * 32 * 256 * sizeof(unsigned), stream);
  hipMemsetAsync(Hf, 0, 16384 * sizeof(float), stream);    // H[0] = 0

  dim3 blk(256);

  // K1 (MFMA, 2-term): XW[t][b][j] = x @ Wih^T + b_lstm  (M=4096,N=2048,K=256)
  gemm_bf16s<2><<<dim3(16, 32, 1), blk, 0, stream>>>(
      x, Wih, XW, bl, 4096, 2048, 256,
      256, 1, 0,            // A: x[m][k], k-contiguous
      256, 1, 0,            // B: Wih[n][k], k-contiguous
      65536, 2048, 128, 0); // C: XW[t=m%128][b=m/128][n]

  // K2: persistent recurrence (EXACT R10 kernel: 32 WGs x 512, sentinel)
  lstm_rec<<<dim3(32), dim3(512), 0, stream>>>(Whh, XW, Hp, Hf, dh, fh);

  // K3: 8-chunk suffix products, A in place, ev_b
  suffix_pre<<<dim3(512), blk, 0, stream>>>(fh, Cp);
  suffix_main<<<dim3(512), blk, 0, stream>>>(dh, fh, Cp, Sp);
  evb_reduce<<<dim3(192), blk, 0, stream>>>(Sp, out + OEB);

  // MLP + readout on last = Hf[128] (tiny, fp32)
  const float* hlast = Hf + 2097152;
  gemm_f32<32, 32, 2, 2><<<dim3(16, 1, 1), blk, 0, stream>>>(
      hlast, Ws1, z1, bs1, 32, 512, 512, 512, 1, 0, 512, 1, 0, 512, 0, 32, 0, 1);
  gemm_f32<32, 32, 2, 2><<<dim3(8, 1, 1), blk, 0, stream>>>(
      z1, Ws2, z2, bs2, 32, 256, 512, 512, 1, 0, 512, 1, 0, 256, 0, 32, 0, 1);
  gemm_f32<32, 32, 2, 2><<<dim3(4, 1, 1), blk, 0, stream>>>(
      z2, Ws3, z3, bs3, 32, 128, 256, 256, 1, 0, 256, 1, 0, 128, 0, 32, 0, 1);
  gemm_f32<32, 32, 2, 2><<<dim3(16, 1, 1), blk, 0, stream>>>(
      z3, Ws4, out + OS, bs4, 32, 512, 128, 128, 1, 0, 128, 1, 0, 512, 0, 32, 0, 0);
  gemm_f32<32, 32, 2, 2><<<dim3(1, 1, 1), blk, 0, stream>>>(
      hlast, Wd, out + OP, bd, 32, 10, 512, 512, 1, 0, 512, 1, 0, 10, 0, 32, 0, 0);

  // K4 (MFMA, 3-term): ev_x[b][j][i] = sum_t A[t][b][j] * x[b][t][i]
  gemm_bf16s<3><<<dim3(2, 12, 32), blk, 0, stream>>>(
      dh, x, out + OEX, nullptr, 1536, 256, 128,
      1, 49152, 1536,       // A: dh[t][b][j], m=j contiguous
      1, 256, 32768,        // B: x[b][t][i], n=i contiguous
      256, 0, 1536, 393216);

  // K5 (MFMA, 3-term): ev_h[b][j][k] = sum_t A[t][b][j] * h_{t-1}[b][k]
  // (runs last: overwrites XW/fh/Hp/Cp/Sp scratch living in the ev_h region)
  gemm_bf16s<3><<<dim3(4, 12, 32), blk, 0, stream>>>(
      dh, Hf, out + OEH, nullptr, 1536, 512, 128,
      1, 49152, 1536,       // A: dh[t][b][j]
      1, 16384, 512,        // B: Hf[t][b][k], n=k contiguous
      512, 0, 1536, 786432);
}